// Round 8
// baseline (8519.070 us; speedup 1.0000x reference)
//
#include <hip/hip_runtime.h>
#include <hip/hip_bf16.h>

typedef unsigned short ushort_t;
typedef unsigned int uint_t;
typedef unsigned long long u64_t;
using f32x4 = __attribute__((ext_vector_type(4))) float;
using bf4 = __attribute__((ext_vector_type(4))) short;
using short8 = __attribute__((ext_vector_type(8))) short;

#define MFMA_B16(a,b,c) __builtin_amdgcn_mfma_f32_16x16x32_bf16((a),(b),(c),0,0,0)
#define MFMA_F8(a,b,c)  __builtin_amdgcn_mfma_f32_16x16x32_fp8_fp8((long)(a),(long)(b),(c),0,0,0)

static __device__ __forceinline__ float bf2f(ushort_t u){
  unsigned v = ((unsigned)u) << 16;
  return __builtin_bit_cast(float, v);
}
static __device__ __forceinline__ ushort_t f2bf(float f){
  __hip_bfloat16 h = __float2bfloat16(f);
  return __builtin_bit_cast(unsigned short, h);
}
static __device__ __forceinline__ f32x4 unpack4(bf4 v){
  f32x4 r;
  r[0]=bf2f((ushort_t)v[0]); r[1]=bf2f((ushort_t)v[1]);
  r[2]=bf2f((ushort_t)v[2]); r[3]=bf2f((ushort_t)v[3]);
  return r;
}
static __device__ __forceinline__ unsigned pack_fp8x4(f32x4 f){
  unsigned u = __builtin_amdgcn_cvt_pk_fp8_f32(f[0], f[1], 0, false);
  u = __builtin_amdgcn_cvt_pk_fp8_f32(f[2], f[3], u, true);
  return u;
}
static __device__ __forceinline__ float frcp(float x){
  return __builtin_amdgcn_rcpf(x);
}

// ws layout:
//   [0, 524288) elems  : bf16 weights, 2048 rows x 256 k (row-major)
//       rows 0-767: xproj B (Wzx^T|Wrx^T|Wtx^T); 768: Wzh^T; 1024: Wrh^T;
//       1280: Wth^T; 1536-2047: Wd^T (1536-1791 mean, 1792-2047 logvar)
//   [524288, 542208)   : bf16 aux (bz|br|btx|bth|bd|h0)
//   byte 1084416       : uint flag (1 = inputs bf16, 0 = f32)
//   byte 1088512       : fp8 weights: Wrh 64K | Wth 64K | Wd_lv 64K
//   byte 2 MB          : Ax bf16 (65536 x 768)
//   byte 112 MB        : eps bf16 (16777216)
#define W_ELEMS  524288
#define AUX_OFF  524288
#define AUX_BTH  768
#define AUX_BD   1024
#define AUX_H0   1536
#define FLAG_BYTE 1084416u
#define F8_OFF_BYTES  1088512u
#define AX_OFF_BYTES  (2u<<20)
#define EPS_OFF_BYTES (112u<<20)
#define ROW_ZH 768
#define ROW_RH 1024
#define ROW_TH 1280
#define ROW_D  1536

// gru LDS map (bytes)
#define L_WZ    0         // 256 rows x 512 B, swizzled (Wzh^T bf16)
#define L_H16   131072    // 16 x 512 B (h bf16)
#define L_HB16  139264    // 16 x 512 B (h_base bf16)
#define L_H8    147456    // 16 x 256 B (h fp8)
#define L_HB8   151552    // 16 x 256 B (h_base fp8)
#define L_BIAS  155648    // bth[256] | bd[512] bf16
#define SMEM_REC 157184

// ---------------------------------------------------------------- dtype detect
__global__ __launch_bounds__(64) void detect_kernel(const uint_t* __restrict__ x,
                                                    uint_t* __restrict__ flag)
{
  int l = threadIdx.x;
  int cnt = 0;
  for (int i = 0; i < 8; ++i){
    uint_t w = x[i*64 + l];
    uint_t e = (w >> 7) & 0xFF;
    unsigned long long m = __ballot(e >= 100 && e <= 136);
    if (l == 0) cnt += __popcll(m);
  }
  if (l == 0) *flag = (cnt >= 256) ? 1u : 0u;
}

// ---------------------------------------------------------------- prep (canonicalize to bf16)
__global__ __launch_bounds__(256) void prep_kernel(
    const void* __restrict__ Wz, const void* __restrict__ Wr,
    const void* __restrict__ Wtx, const void* __restrict__ Wth,
    const void* __restrict__ Wd,
    const void* __restrict__ bz, const void* __restrict__ br,
    const void* __restrict__ btx, const void* __restrict__ bth,
    const void* __restrict__ bd, const void* __restrict__ h0,
    const uint_t* __restrict__ flag, ushort_t* __restrict__ o)
{
  const bool b16 = (*flag != 0);
  int i = blockIdx.x * 256 + threadIdx.x;          // < 542208
  const void* src; int idx;
  if (i < W_ELEMS){
    int row = i >> 8, k = i & 255;
    if      (row <  256){ src = Wz;  idx = k*256 + row;         }
    else if (row <  512){ src = Wr;  idx = k*256 + (row-256);   }
    else if (row <  768){ src = Wtx; idx = k*256 + (row-512);   }
    else if (row < 1024){ src = Wz;  idx = (256+k)*256 + (row-768);  }
    else if (row < 1280){ src = Wr;  idx = (256+k)*256 + (row-1024); }
    else if (row < 1536){ src = Wth; idx = k*256 + (row-1280);  }
    else                { src = Wd;  idx = k*512 + (row-1536);  }
  } else {
    int j = i - W_ELEMS;
    if      (j <  256){ src = bz;  idx = j;       }
    else if (j <  512){ src = br;  idx = j-256;   }
    else if (j <  768){ src = btx; idx = j-512;   }
    else if (j < 1024){ src = bth; idx = j-768;   }
    else if (j < 1536){ src = bd;  idx = j-1024;  }
    else              { src = h0;  idx = j-1536;  }
  }
  o[i] = b16 ? ((const ushort_t*)src)[idx] : f2bf(((const float*)src)[idx]);
}

// ---------------------------------------------------------------- prep fp8 (Wrh|Wth|Wd_lv)
__global__ __launch_bounds__(256) void prep_f8_kernel(
    const ushort_t* __restrict__ ws, unsigned char* __restrict__ o)
{
  int i = blockIdx.x * 256 + threadIdx.x;          // < 49152, 4 elems each
  int m = i >> 14;                                 // region 0,1,2
  int b = (i & 16383) * 4;                         // byte offset in 64K region
  int row = b >> 8, k = b & 255;
  int srow = (m == 0) ? (ROW_RH + row) : (m == 1) ? (ROW_TH + row) : (ROW_D + 256 + row);
  f32x4 f = unpack4(*reinterpret_cast<const bf4*>(ws + srow*256 + k));
  *reinterpret_cast<unsigned*>(o + (size_t)i*4) = pack_fp8x4(f);
}

// ---------------------------------------------------------------- eps -> bf16
__global__ __launch_bounds__(256) void epscvt_kernel(
    const void* __restrict__ eps, const uint_t* __restrict__ flag,
    ushort_t* __restrict__ o)
{
  const bool b16 = (*flag != 0);
  int i = blockIdx.x * 256 + threadIdx.x;          // 8 elems each, 16777216 total
  if (b16){
    short8 v = reinterpret_cast<const short8*>(eps)[i];
    reinterpret_cast<short8*>(o)[i] = v;
  } else {
    const f32x4* e = reinterpret_cast<const f32x4*>(eps) + i*2;
    f32x4 a = e[0], b = e[1];
    short8 v;
    v[0]=(short)f2bf(a[0]); v[1]=(short)f2bf(a[1]); v[2]=(short)f2bf(a[2]); v[3]=(short)f2bf(a[3]);
    v[4]=(short)f2bf(b[0]); v[5]=(short)f2bf(b[1]); v[6]=(short)f2bf(b[2]); v[7]=(short)f2bf(b[3]);
    reinterpret_cast<short8*>(o)[i] = v;
  }
}

// ---------------------------------------------------------------- x projection GEMM
__global__ __launch_bounds__(256) void xproj_kernel(
    const void* __restrict__ x, const ushort_t* __restrict__ wsB,
    const ushort_t* __restrict__ aux, const uint_t* __restrict__ flag,
    ushort_t* __restrict__ Ax)
{
  __shared__ ushort_t As[32768];
  const bool b16 = (*flag != 0);
  const int tid = threadIdx.x, w = tid >> 6, l = tid & 63, lr = l & 15, lg = l >> 4;
  const int mt = blockIdx.x % 512, nb = blockIdx.x / 512;
  const int m0 = mt * 128, n0 = nb * 128;

  #pragma unroll
  for (int i = 0; i < 16; ++i){
    int gidx = i*256 + tid, row = gidx >> 5, g = gidx & 31;
    short8 v;
    if (b16){
      v = *reinterpret_cast<const short8*>((const ushort_t*)x + (m0+row)*256 + g*8);
    } else {
      const f32x4* xf = reinterpret_cast<const f32x4*>((const float*)x + (m0+row)*256 + g*8);
      f32x4 a0 = xf[0], a1 = xf[1];
      v[0]=(short)f2bf(a0[0]); v[1]=(short)f2bf(a0[1]); v[2]=(short)f2bf(a0[2]); v[3]=(short)f2bf(a0[3]);
      v[4]=(short)f2bf(a1[0]); v[5]=(short)f2bf(a1[1]); v[6]=(short)f2bf(a1[2]); v[7]=(short)f2bf(a1[3]);
    }
    *reinterpret_cast<short8*>(reinterpret_cast<char*>(As) + row*512 + ((g ^ (row&7)) << 4)) = v;
  }
  __syncthreads();

  const int wr = w >> 1, wc = w & 1;
  f32x4 acc[4][4];
  #pragma unroll
  for (int a = 0; a < 4; ++a)
    #pragma unroll
    for (int b = 0; b < 4; ++b) acc[a][b] = (f32x4){0.f,0.f,0.f,0.f};

  #pragma unroll
  for (int ks = 0; ks < 8; ++ks){
    short8 av[4], bv[4];
    #pragma unroll
    for (int mi = 0; mi < 4; ++mi){
      int rT = 64*wr + 16*mi + lr, g = ks*4 + lg;
      av[mi] = *reinterpret_cast<const short8*>(reinterpret_cast<const char*>(As) + rT*512 + ((g ^ (rT&7)) << 4));
    }
    #pragma unroll
    for (int ni = 0; ni < 4; ++ni){
      int nr = n0 + 64*wc + 16*ni + lr;
      bv[ni] = *reinterpret_cast<const short8*>(wsB + nr*256 + ks*32 + lg*8);
    }
    #pragma unroll
    for (int mi = 0; mi < 4; ++mi)
      #pragma unroll
      for (int ni = 0; ni < 4; ++ni)
        acc[mi][ni] = MFMA_B16(av[mi], bv[ni], acc[mi][ni]);
  }

  #pragma unroll
  for (int ni = 0; ni < 4; ++ni){
    int c = n0 + 64*wc + 16*ni + lr;
    float bias = bf2f(aux[c]);
    #pragma unroll
    for (int mi = 0; mi < 4; ++mi)
      #pragma unroll
      for (int j = 0; j < 4; ++j){
        int m = m0 + 64*wr + 16*mi + lg*4 + j;
        Ax[m*768 + c] = f2bf(acc[mi][ni][j] + bias);
      }
  }
}

// ---------------------------------------------------------------- recurrent kernel
// 4 WGs x 1024 threads (16 waves, 4/SIMD). WG owns batch rows [16*bid,+16);
// wave w owns cols [16w, 16w+16). Operand-swapped MFMA: D = W(A) x h(B);
// lane holds (batch = lane&15, cols = 16w + (lane>>4)*4 + q).
// ALL weights resident: Wzh bf16 in LDS; Wrh/Wth/Wd_lv fp8 + Wd_mean bf16 in regs.
// Per-step VMEM = Ax (3xb64) + eps (1xb64).
__global__ __attribute__((amdgpu_flat_work_group_size(1024, 1024)))
void gru_kernel(
    const ushort_t* __restrict__ ws16, const unsigned char* __restrict__ f8w,
    const ushort_t* __restrict__ Ax, const ushort_t* __restrict__ eps16,
    const uint_t* __restrict__ flag, void* __restrict__ outp)
{
  extern __shared__ char smem[];
  const bool b16 = (*flag != 0);
  ushort_t* o16 = (ushort_t*)outp;
  float*    o32 = (float*)outp;
  const ushort_t* aux = ws16 + AUX_OFF;
  ushort_t* bias_lds = (ushort_t*)(smem + L_BIAS);
  const int tid = threadIdx.x, w = tid >> 6, l = tid & 63, lr = l & 15, lg = l >> 4;
  const int b0 = blockIdx.x * 16;
  const int c0 = 16 * w;
  const int cl = c0 + lg*4;                 // lane's 4-col base

  // stage Wzh^T into LDS (swizzled, granule 16B, XOR row&15)
  for (int gi = tid; gi < 8192; gi += 1024){
    int row = gi >> 5, g = gi & 31;
    short8 v = *reinterpret_cast<const short8*>(ws16 + (ROW_ZH + row)*256 + g*8);
    *reinterpret_cast<short8*>(smem + row*512 + ((g ^ (row&15)) << 4)) = v;
  }
  if (tid < 256) bias_lds[tid] = aux[AUX_BTH + tid];
  if (tid < 512) bias_lds[256 + tid] = aux[AUX_BD + tid];

  // resident weight fragments (one 16-col tile per wave)
  const unsigned char* f_rh = f8w;
  const unsigned char* f_th = f8w + 65536;
  const unsigned char* f_dl = f8w + 131072;
  u64_t wrh8[8], wth8[8], wdl8[8];
  short8 wdm[8];
  {
    int r = c0 + lr;
    #pragma unroll
    for (int ks = 0; ks < 8; ++ks){
      wrh8[ks] = *reinterpret_cast<const u64_t*>(f_rh + r*256 + ks*32 + lg*8);
      wth8[ks] = *reinterpret_cast<const u64_t*>(f_th + r*256 + ks*32 + lg*8);
      wdl8[ks] = *reinterpret_cast<const u64_t*>(f_dl + r*256 + ks*32 + lg*8);
      wdm[ks]  = *reinterpret_cast<const short8*>(ws16 + (ROW_D + r)*256 + ks*32 + lg*8);
    }
  }

  // h in fp32 regs; lane holds (batch=lr, cols cl+q)
  f32x4 hreg;
  {
    int c = cl, g = c >> 3;
    hreg = unpack4(*reinterpret_cast<const bf4*>(aux + AUX_H0 + (b0+lr)*256 + c));
    bf4 hv;
    hv[0]=(short)f2bf(hreg[0]); hv[1]=(short)f2bf(hreg[1]);
    hv[2]=(short)f2bf(hreg[2]); hv[3]=(short)f2bf(hreg[3]);
    *reinterpret_cast<bf4*>(smem + L_H16 + lr*512 + ((g ^ (lr&15)) << 4) + (c&7)*2) = hv;
    *reinterpret_cast<unsigned*>(smem + L_H8 + lr*256 + ((g ^ (lr&15)) << 3) + (c&7)) = pack_fp8x4(hreg);
  }
  __syncthreads();

  const ushort_t* apt = Ax    + (size_t)(b0+lr)*1024*768 + cl;
  const ushort_t* ept = eps16 + (size_t)(b0+lr)*1024*256 + cl;
  size_t obase = (size_t)(b0+lr)*262144 + cl;

  for (int t = 0; t < 1024; ++t){
    // this step's global loads (4 x b64), issued up front, consumed late
    bf4 axzp = *reinterpret_cast<const bf4*>(apt);
    bf4 axrp = *reinterpret_cast<const bf4*>(apt + 256);
    bf4 axtp = *reinterpret_cast<const bf4*>(apt + 512);
    bf4 epsp = *reinterpret_cast<const bf4*>(ept);

    // ---- phase 1: z (bf16), r (fp8), h@Wth (fp8)
    f32x4 az = (f32x4){0.f,0.f,0.f,0.f};
    f32x4 ar = az;
    f32x4 at = unpack4(*reinterpret_cast<const bf4*>(bias_lds + cl));
    #pragma unroll
    for (int ks = 0; ks < 8; ++ks){
      const int g = ks*4 + lg;
      short8 hB = *reinterpret_cast<const short8*>(smem + L_H16 + lr*512 + ((g ^ (lr&15)) << 4));
      u64_t  h8 = *reinterpret_cast<const u64_t*>(smem + L_H8 + lr*256 + ((g ^ (lr&15)) << 3));
      int nc = c0 + lr;
      short8 wz = *reinterpret_cast<const short8*>(smem + nc*512 + ((g ^ (nc&15)) << 4));
      az = MFMA_B16(wz, hB, az);
      ar = MFMA_F8(wrh8[ks], h8, ar);
      at = MFMA_F8(wth8[ks], h8, at);
    }

    // activations -> h_base (bf16 + fp8 copies into LDS)
    {
      f32x4 axz = unpack4(axzp), axr = unpack4(axrp), axt = unpack4(axtp);
      f32x4 hb;
      bf4 hb4;
      #pragma unroll
      for (int q = 0; q < 4; ++q){
        float zp = az[q] + axz[q];
        float rp = ar[q] + axr[q];
        float zv = frcp(1.f + __expf(-zp));
        float rv = frcp(1.f + __expf(-rp));
        float tp = axt[q] + rv*at[q];
        float e2 = __expf(-2.f*fabsf(tp));
        float tv = (1.f - e2) * frcp(1.f + e2);
        tv = (tp < 0.f) ? -tv : tv;
        hb[q] = zv*hreg[q] + (1.f - zv)*tv;
        hb4[q] = (short)f2bf(hb[q]);
      }
      int c = cl, g = c >> 3;
      *reinterpret_cast<bf4*>(smem + L_HB16 + lr*512 + ((g ^ (lr&15)) << 4) + (c&7)*2) = hb4;
      *reinterpret_cast<unsigned*>(smem + L_HB8 + lr*256 + ((g ^ (lr&15)) << 3) + (c&7)) = pack_fp8x4(hb);
    }
    asm volatile("s_waitcnt lgkmcnt(0)" ::: "memory");
    __builtin_amdgcn_s_barrier();
    asm volatile("" ::: "memory");

    // ---- phase 2: mean (bf16, wdm) + logvar (fp8, wdl8) — all resident
    f32x4 apm = unpack4(*reinterpret_cast<const bf4*>(bias_lds + 256 + cl));
    f32x4 apl = unpack4(*reinterpret_cast<const bf4*>(bias_lds + 512 + cl));
    #pragma unroll
    for (int ks = 0; ks < 8; ++ks){
      const int g = ks*4 + lg;
      short8 hbB = *reinterpret_cast<const short8*>(smem + L_HB16 + lr*512 + ((g ^ (lr&15)) << 4));
      u64_t  hb8 = *reinterpret_cast<const u64_t*>(smem + L_HB8 + lr*256 + ((g ^ (lr&15)) << 3));
      apm = MFMA_B16(wdm[ks], hbB, apm);
      apl = MFMA_F8(wdl8[ks], hb8, apl);
    }

    // ---- sample + write h
    {
      f32x4 epsv = unpack4(epsp);
      bf4 s4;
      f32x4 sf;
      #pragma unroll
      for (int q = 0; q < 4; ++q){
        float mean = fminf(fmaxf(apm[q], -1000.f), 1000.f);
        float lvv  = fminf(fmaxf(apl[q], -30.f),   30.f);
        float s = mean + __expf(0.5f*lvv)*epsv[q];
        hreg[q] = s;
        sf[q] = s;
        s4[q] = (short)f2bf(s);
      }
      int c = cl, g = c >> 3;
      *reinterpret_cast<bf4*>(smem + L_H16 + lr*512 + ((g ^ (lr&15)) << 4) + (c&7)*2) = s4;
      *reinterpret_cast<unsigned*>(smem + L_H8 + lr*256 + ((g ^ (lr&15)) << 3) + (c&7)) = pack_fp8x4(sf);
      if (b16){
        *reinterpret_cast<bf4*>(o16 + obase) = s4;
        if (t == 1023) *reinterpret_cast<bf4*>(o16 + 16777216u + (size_t)(b0+lr)*256 + c) = s4;
      } else {
        *reinterpret_cast<f32x4*>(o32 + obase) = sf;
        if (t == 1023) *reinterpret_cast<f32x4*>(o32 + 16777216u + (size_t)(b0+lr)*256 + c) = sf;
      }
    }
    asm volatile("s_waitcnt lgkmcnt(0)" ::: "memory");
    __builtin_amdgcn_s_barrier();
    asm volatile("" ::: "memory");

    apt += 768; ept += 256; obase += 256;
  }
}

// ---------------------------------------------------------------- host
extern "C" void kernel_launch(void* const* d_in, const int* in_sizes, int n_in,
                              void* d_out, int out_size, void* d_ws, size_t ws_size,
                              hipStream_t stream)
{
  const void* x   = d_in[0];
  const void* h0  = d_in[1];
  const void* eps = d_in[2];
  const void* Wz  = d_in[3];
  const void* bz  = d_in[4];
  const void* Wr  = d_in[5];
  const void* br  = d_in[6];
  const void* Wtx = d_in[7];
  const void* btx = d_in[8];
  const void* Wth = d_in[9];
  const void* bth = d_in[10];
  const void* Wd  = d_in[11];
  const void* bd  = d_in[12];
  ushort_t* ws16 = (ushort_t*)d_ws;
  uint_t* flag = (uint_t*)((char*)d_ws + FLAG_BYTE);
  const ushort_t* aux = ws16 + AUX_OFF;
  unsigned char* f8w = (unsigned char*)d_ws + F8_OFF_BYTES;
  ushort_t* Ax = (ushort_t*)((char*)d_ws + AX_OFF_BYTES);
  ushort_t* eps16 = (ushort_t*)((char*)d_ws + EPS_OFF_BYTES);

  detect_kernel<<<dim3(1), dim3(64), 0, stream>>>((const uint_t*)x, flag);
  prep_kernel<<<dim3(2118), dim3(256), 0, stream>>>(Wz, Wr, Wtx, Wth, Wd,
                                                    bz, br, btx, bth, bd, h0,
                                                    flag, ws16);
  prep_f8_kernel<<<dim3(192), dim3(256), 0, stream>>>(ws16, f8w);
  epscvt_kernel<<<dim3(8192), dim3(256), 0, stream>>>(eps, flag, eps16);
  xproj_kernel<<<dim3(3072), dim3(256), 0, stream>>>(x, ws16, aux, flag, Ax);

  (void)hipFuncSetAttribute(reinterpret_cast<const void*>(&gru_kernel),
                            hipFuncAttributeMaxDynamicSharedMemorySize, SMEM_REC);
  gru_kernel<<<dim3(4), dim3(1024), SMEM_REC, stream>>>(ws16, f8w, Ax, eps16, flag, d_out);
}

// Round 9
// 6168.731 us; speedup vs baseline: 1.3810x; 1.3810x over previous
//
#include <hip/hip_runtime.h>
#include <hip/hip_bf16.h>

typedef unsigned short ushort_t;
typedef unsigned int uint_t;
typedef unsigned long long u64_t;
using f32x4 = __attribute__((ext_vector_type(4))) float;
using bf4 = __attribute__((ext_vector_type(4))) short;
using short8 = __attribute__((ext_vector_type(8))) short;

#define MFMA_B16(a,b,c) __builtin_amdgcn_mfma_f32_16x16x32_bf16((a),(b),(c),0,0,0)
#define MFMA_F8(a,b,c)  __builtin_amdgcn_mfma_f32_16x16x32_fp8_fp8((long)(a),(long)(b),(c),0,0,0)

static __device__ __forceinline__ float bf2f(ushort_t u){
  unsigned v = ((unsigned)u) << 16;
  return __builtin_bit_cast(float, v);
}
static __device__ __forceinline__ ushort_t f2bf(float f){
  __hip_bfloat16 h = __float2bfloat16(f);
  return __builtin_bit_cast(unsigned short, h);
}
static __device__ __forceinline__ f32x4 unpack4(bf4 v){
  f32x4 r;
  r[0]=bf2f((ushort_t)v[0]); r[1]=bf2f((ushort_t)v[1]);
  r[2]=bf2f((ushort_t)v[2]); r[3]=bf2f((ushort_t)v[3]);
  return r;
}
static __device__ __forceinline__ unsigned pack_fp8x4(f32x4 f){
  unsigned u = __builtin_amdgcn_cvt_pk_fp8_f32(f[0], f[1], 0, false);
  u = __builtin_amdgcn_cvt_pk_fp8_f32(f[2], f[3], u, true);
  return u;
}

// ws layout:
//   [0, 524288) elems  : bf16 weights, 2048 rows x 256 k (row-major)
//       rows 0-767: xproj B (Wzx^T|Wrx^T|Wtx^T); 768: Wzh^T; 1024: Wrh^T;
//       1280: Wth^T; 1536-2047: Wd^T (1536-1791 mean, 1792-2047 logvar)
//   [524288, 542208)   : bf16 aux (bz|br|btx|bth|bd|h0)
//   byte 1084416       : uint flag (1 = inputs bf16, 0 = f32)
//   byte 1088512       : fp8 weights: Wrh 64K | Wth 64K | Wd_lv 64K
//   byte 2 MB          : Ax bf16 (65536 x 768)
//   byte 112 MB        : eps bf16 (16777216)
#define W_ELEMS  524288
#define AUX_OFF  524288
#define AUX_BTH  768
#define AUX_BD   1024
#define AUX_H0   1536
#define FLAG_BYTE 1084416u
#define F8_OFF_BYTES  1088512u
#define AX_OFF_BYTES  (2u<<20)
#define EPS_OFF_BYTES (112u<<20)
#define ROW_ZH 768
#define ROW_RH 1024
#define ROW_TH 1280
#define ROW_D  1536

// gru LDS map (bytes)
#define L_WZ    0         // 256 rows x 512 B, swizzled (Wzh^T bf16)
#define L_H16   131072    // 16 x 512 B (h bf16)
#define L_HB16  139264    // 16 x 512 B (h_base bf16)
#define L_H8    147456    // 16 x 256 B (h fp8)
#define L_HB8   151552    // 16 x 256 B (h_base fp8)
#define L_BIAS  155648    // bth[256] | bd[512] bf16
#define SMEM_REC 157184

// ---------------------------------------------------------------- dtype detect
__global__ __launch_bounds__(64) void detect_kernel(const uint_t* __restrict__ x,
                                                    uint_t* __restrict__ flag)
{
  int l = threadIdx.x;
  int cnt = 0;
  for (int i = 0; i < 8; ++i){
    uint_t w = x[i*64 + l];
    uint_t e = (w >> 7) & 0xFF;
    unsigned long long m = __ballot(e >= 100 && e <= 136);
    if (l == 0) cnt += __popcll(m);
  }
  if (l == 0) *flag = (cnt >= 256) ? 1u : 0u;
}

// ---------------------------------------------------------------- prep (canonicalize to bf16)
__global__ __launch_bounds__(256) void prep_kernel(
    const void* __restrict__ Wz, const void* __restrict__ Wr,
    const void* __restrict__ Wtx, const void* __restrict__ Wth,
    const void* __restrict__ Wd,
    const void* __restrict__ bz, const void* __restrict__ br,
    const void* __restrict__ btx, const void* __restrict__ bth,
    const void* __restrict__ bd, const void* __restrict__ h0,
    const uint_t* __restrict__ flag, ushort_t* __restrict__ o)
{
  const bool b16 = (*flag != 0);
  int i = blockIdx.x * 256 + threadIdx.x;          // < 542208
  const void* src; int idx;
  if (i < W_ELEMS){
    int row = i >> 8, k = i & 255;
    if      (row <  256){ src = Wz;  idx = k*256 + row;         }
    else if (row <  512){ src = Wr;  idx = k*256 + (row-256);   }
    else if (row <  768){ src = Wtx; idx = k*256 + (row-512);   }
    else if (row < 1024){ src = Wz;  idx = (256+k)*256 + (row-768);  }
    else if (row < 1280){ src = Wr;  idx = (256+k)*256 + (row-1024); }
    else if (row < 1536){ src = Wth; idx = k*256 + (row-1280);  }
    else                { src = Wd;  idx = k*512 + (row-1536);  }
  } else {
    int j = i - W_ELEMS;
    if      (j <  256){ src = bz;  idx = j;       }
    else if (j <  512){ src = br;  idx = j-256;   }
    else if (j <  768){ src = btx; idx = j-512;   }
    else if (j < 1024){ src = bth; idx = j-768;   }
    else if (j < 1536){ src = bd;  idx = j-1024;  }
    else              { src = h0;  idx = j-1536;  }
  }
  o[i] = b16 ? ((const ushort_t*)src)[idx] : f2bf(((const float*)src)[idx]);
}

// ---------------------------------------------------------------- prep fp8 (Wrh|Wth|Wd_lv)
__global__ __launch_bounds__(256) void prep_f8_kernel(
    const ushort_t* __restrict__ ws, unsigned char* __restrict__ o)
{
  int i = blockIdx.x * 256 + threadIdx.x;          // < 49152, 4 elems each
  int m = i >> 14;                                 // region 0,1,2
  int b = (i & 16383) * 4;                         // byte offset in 64K region
  int row = b >> 8, k = b & 255;
  int srow = (m == 0) ? (ROW_RH + row) : (m == 1) ? (ROW_TH + row) : (ROW_D + 256 + row);
  f32x4 f = unpack4(*reinterpret_cast<const bf4*>(ws + srow*256 + k));
  *reinterpret_cast<unsigned*>(o + (size_t)i*4) = pack_fp8x4(f);
}

// ---------------------------------------------------------------- eps -> bf16
__global__ __launch_bounds__(256) void epscvt_kernel(
    const void* __restrict__ eps, const uint_t* __restrict__ flag,
    ushort_t* __restrict__ o)
{
  const bool b16 = (*flag != 0);
  int i = blockIdx.x * 256 + threadIdx.x;          // 8 elems each, 16777216 total
  if (b16){
    short8 v = reinterpret_cast<const short8*>(eps)[i];
    reinterpret_cast<short8*>(o)[i] = v;
  } else {
    const f32x4* e = reinterpret_cast<const f32x4*>(eps) + i*2;
    f32x4 a = e[0], b = e[1];
    short8 v;
    v[0]=(short)f2bf(a[0]); v[1]=(short)f2bf(a[1]); v[2]=(short)f2bf(a[2]); v[3]=(short)f2bf(a[3]);
    v[4]=(short)f2bf(b[0]); v[5]=(short)f2bf(b[1]); v[6]=(short)f2bf(b[2]); v[7]=(short)f2bf(b[3]);
    reinterpret_cast<short8*>(o)[i] = v;
  }
}

// ---------------------------------------------------------------- x projection GEMM
__global__ __launch_bounds__(256) void xproj_kernel(
    const void* __restrict__ x, const ushort_t* __restrict__ wsB,
    const ushort_t* __restrict__ aux, const uint_t* __restrict__ flag,
    ushort_t* __restrict__ Ax)
{
  __shared__ ushort_t As[32768];
  const bool b16 = (*flag != 0);
  const int tid = threadIdx.x, w = tid >> 6, l = tid & 63, lr = l & 15, lg = l >> 4;
  const int mt = blockIdx.x % 512, nb = blockIdx.x / 512;
  const int m0 = mt * 128, n0 = nb * 128;

  #pragma unroll
  for (int i = 0; i < 16; ++i){
    int gidx = i*256 + tid, row = gidx >> 5, g = gidx & 31;
    short8 v;
    if (b16){
      v = *reinterpret_cast<const short8*>((const ushort_t*)x + (m0+row)*256 + g*8);
    } else {
      const f32x4* xf = reinterpret_cast<const f32x4*>((const float*)x + (m0+row)*256 + g*8);
      f32x4 a0 = xf[0], a1 = xf[1];
      v[0]=(short)f2bf(a0[0]); v[1]=(short)f2bf(a0[1]); v[2]=(short)f2bf(a0[2]); v[3]=(short)f2bf(a0[3]);
      v[4]=(short)f2bf(a1[0]); v[5]=(short)f2bf(a1[1]); v[6]=(short)f2bf(a1[2]); v[7]=(short)f2bf(a1[3]);
    }
    *reinterpret_cast<short8*>(reinterpret_cast<char*>(As) + row*512 + ((g ^ (row&7)) << 4)) = v;
  }
  __syncthreads();

  const int wr = w >> 1, wc = w & 1;
  f32x4 acc[4][4];
  #pragma unroll
  for (int a = 0; a < 4; ++a)
    #pragma unroll
    for (int b = 0; b < 4; ++b) acc[a][b] = (f32x4){0.f,0.f,0.f,0.f};

  #pragma unroll
  for (int ks = 0; ks < 8; ++ks){
    short8 av[4], bv[4];
    #pragma unroll
    for (int mi = 0; mi < 4; ++mi){
      int rT = 64*wr + 16*mi + lr, g = ks*4 + lg;
      av[mi] = *reinterpret_cast<const short8*>(reinterpret_cast<const char*>(As) + rT*512 + ((g ^ (rT&7)) << 4));
    }
    #pragma unroll
    for (int ni = 0; ni < 4; ++ni){
      int nr = n0 + 64*wc + 16*ni + lr;
      bv[ni] = *reinterpret_cast<const short8*>(wsB + nr*256 + ks*32 + lg*8);
    }
    #pragma unroll
    for (int mi = 0; mi < 4; ++mi)
      #pragma unroll
      for (int ni = 0; ni < 4; ++ni)
        acc[mi][ni] = MFMA_B16(av[mi], bv[ni], acc[mi][ni]);
  }

  #pragma unroll
  for (int ni = 0; ni < 4; ++ni){
    int c = n0 + 64*wc + 16*ni + lr;
    float bias = bf2f(aux[c]);
    #pragma unroll
    for (int mi = 0; mi < 4; ++mi)
      #pragma unroll
      for (int j = 0; j < 4; ++j){
        int m = m0 + 64*wr + 16*mi + lg*4 + j;
        Ax[m*768 + c] = f2bf(acc[mi][ni][j] + bias);
      }
  }
}

// ---------------------------------------------------------------- recurrent kernel
// 4 WGs x 1024 threads (16 waves, pinned 4/SIMD -> 128 VGPR budget).
// WG owns batch rows [16*bid,+16); wave w owns cols [16w, 16w+16).
// Operand-swapped MFMA: D = W(A) x h(B); lane holds
// (batch = lane&15, cols = 16w + (lane>>4)*4 + q).
// ALL weights resident: Wzh bf16 in LDS; Wrh/Wth/Wd_lv fp8 + Wd_mean bf16 in regs.
// Per-step VMEM = Ax (3xb64) + eps (1xb64).
__global__ __attribute__((amdgpu_flat_work_group_size(1024, 1024),
                          amdgpu_waves_per_eu(4, 4)))
void gru_kernel(
    const ushort_t* __restrict__ ws16, const unsigned char* __restrict__ f8w,
    const ushort_t* __restrict__ Ax, const ushort_t* __restrict__ eps16,
    const uint_t* __restrict__ flag, void* __restrict__ outp)
{
  extern __shared__ char smem[];
  const bool b16 = (*flag != 0);
  ushort_t* o16 = (ushort_t*)outp;
  float*    o32 = (float*)outp;
  const ushort_t* aux = ws16 + AUX_OFF;
  ushort_t* bias_lds = (ushort_t*)(smem + L_BIAS);
  const int tid = threadIdx.x, w = tid >> 6, l = tid & 63, lr = l & 15, lg = l >> 4;
  const int b0 = blockIdx.x * 16;
  const int c0 = 16 * w;
  const int cl = c0 + lg*4;                 // lane's 4-col base

  // stage Wzh^T into LDS (swizzled, granule 16B, XOR row&15)
  for (int gi = tid; gi < 8192; gi += 1024){
    int row = gi >> 5, g = gi & 31;
    short8 v = *reinterpret_cast<const short8*>(ws16 + (ROW_ZH + row)*256 + g*8);
    *reinterpret_cast<short8*>(smem + row*512 + ((g ^ (row&15)) << 4)) = v;
  }
  if (tid < 256) bias_lds[tid] = aux[AUX_BTH + tid];
  if (tid < 512) bias_lds[256 + tid] = aux[AUX_BD + tid];

  // resident weight fragments (one 16-col tile per wave)
  const unsigned char* f_rh = f8w;
  const unsigned char* f_th = f8w + 65536;
  const unsigned char* f_dl = f8w + 131072;
  u64_t wrh8[8], wth8[8], wdl8[8];
  short8 wdm[8];
  {
    int r = c0 + lr;
    #pragma unroll
    for (int ks = 0; ks < 8; ++ks){
      wrh8[ks] = *reinterpret_cast<const u64_t*>(f_rh + r*256 + ks*32 + lg*8);
      wth8[ks] = *reinterpret_cast<const u64_t*>(f_th + r*256 + ks*32 + lg*8);
      wdl8[ks] = *reinterpret_cast<const u64_t*>(f_dl + r*256 + ks*32 + lg*8);
      wdm[ks]  = *reinterpret_cast<const short8*>(ws16 + (ROW_D + r)*256 + ks*32 + lg*8);
    }
  }

  // h in fp32 regs; lane holds (batch=lr, cols cl+q)
  f32x4 hreg;
  {
    int c = cl, g = c >> 3;
    hreg = unpack4(*reinterpret_cast<const bf4*>(aux + AUX_H0 + (b0+lr)*256 + c));
    bf4 hv;
    hv[0]=(short)f2bf(hreg[0]); hv[1]=(short)f2bf(hreg[1]);
    hv[2]=(short)f2bf(hreg[2]); hv[3]=(short)f2bf(hreg[3]);
    *reinterpret_cast<bf4*>(smem + L_H16 + lr*512 + ((g ^ (lr&15)) << 4) + (c&7)*2) = hv;
    *reinterpret_cast<unsigned*>(smem + L_H8 + lr*256 + ((g ^ (lr&15)) << 3) + (c&7)) = pack_fp8x4(hreg);
  }
  __syncthreads();

  const ushort_t* apt = Ax    + (size_t)(b0+lr)*1024*768 + cl;
  const ushort_t* ept = eps16 + (size_t)(b0+lr)*1024*256 + cl;
  size_t obase = (size_t)(b0+lr)*262144 + cl;

  for (int t = 0; t < 1024; ++t){
    // this step's global loads (4 x b64), issued up front, consumed late
    bf4 axzp = *reinterpret_cast<const bf4*>(apt);
    bf4 axrp = *reinterpret_cast<const bf4*>(apt + 256);
    bf4 axtp = *reinterpret_cast<const bf4*>(apt + 512);
    bf4 epsp = *reinterpret_cast<const bf4*>(ept);

    // ---- phase 1: z (bf16), r (fp8), h@Wth (fp8)
    f32x4 az = (f32x4){0.f,0.f,0.f,0.f};
    f32x4 ar = az;
    f32x4 at = unpack4(*reinterpret_cast<const bf4*>(bias_lds + cl));
    #pragma unroll
    for (int ks = 0; ks < 8; ++ks){
      const int g = ks*4 + lg;
      short8 hB = *reinterpret_cast<const short8*>(smem + L_H16 + lr*512 + ((g ^ (lr&15)) << 4));
      u64_t  h8 = *reinterpret_cast<const u64_t*>(smem + L_H8 + lr*256 + ((g ^ (lr&15)) << 3));
      int nc = c0 + lr;
      short8 wz = *reinterpret_cast<const short8*>(smem + nc*512 + ((g ^ (nc&15)) << 4));
      az = MFMA_B16(wz, hB, az);
      ar = MFMA_F8(wrh8[ks], h8, ar);
      at = MFMA_F8(wth8[ks], h8, at);
    }

    // activations -> h_base (bf16 + fp8 copies into LDS)
    {
      f32x4 axz = unpack4(axzp), axr = unpack4(axrp), axt = unpack4(axtp);
      f32x4 hb;
      bf4 hb4;
      #pragma unroll
      for (int q = 0; q < 4; ++q){
        float zp = az[q] + axz[q];
        float rp = ar[q] + axr[q];
        float zv = 1.f/(1.f + __expf(-zp));
        float rv = 1.f/(1.f + __expf(-rp));
        float tp = axt[q] + rv*at[q];
        float e2 = __expf(-2.f*fabsf(tp));
        float tv = (1.f - e2)/(1.f + e2);
        tv = (tp < 0.f) ? -tv : tv;
        hb[q] = zv*hreg[q] + (1.f - zv)*tv;
        hb4[q] = (short)f2bf(hb[q]);
      }
      int c = cl, g = c >> 3;
      *reinterpret_cast<bf4*>(smem + L_HB16 + lr*512 + ((g ^ (lr&15)) << 4) + (c&7)*2) = hb4;
      *reinterpret_cast<unsigned*>(smem + L_HB8 + lr*256 + ((g ^ (lr&15)) << 3) + (c&7)) = pack_fp8x4(hb);
    }
    asm volatile("s_waitcnt lgkmcnt(0)" ::: "memory");
    __builtin_amdgcn_s_barrier();
    asm volatile("" ::: "memory");

    // ---- phase 2: mean (bf16, wdm) + logvar (fp8, wdl8) — all resident
    f32x4 apm = unpack4(*reinterpret_cast<const bf4*>(bias_lds + 256 + cl));
    f32x4 apl = unpack4(*reinterpret_cast<const bf4*>(bias_lds + 512 + cl));
    #pragma unroll
    for (int ks = 0; ks < 8; ++ks){
      const int g = ks*4 + lg;
      short8 hbB = *reinterpret_cast<const short8*>(smem + L_HB16 + lr*512 + ((g ^ (lr&15)) << 4));
      u64_t  hb8 = *reinterpret_cast<const u64_t*>(smem + L_HB8 + lr*256 + ((g ^ (lr&15)) << 3));
      apm = MFMA_B16(wdm[ks], hbB, apm);
      apl = MFMA_F8(wdl8[ks], hb8, apl);
    }

    // ---- sample + write h
    {
      f32x4 epsv = unpack4(epsp);
      bf4 s4;
      f32x4 sf;
      #pragma unroll
      for (int q = 0; q < 4; ++q){
        float mean = fminf(fmaxf(apm[q], -1000.f), 1000.f);
        float lvv  = fminf(fmaxf(apl[q], -30.f),   30.f);
        float s = mean + __expf(0.5f*lvv)*epsv[q];
        hreg[q] = s;
        sf[q] = s;
        s4[q] = (short)f2bf(s);
      }
      int c = cl, g = c >> 3;
      *reinterpret_cast<bf4*>(smem + L_H16 + lr*512 + ((g ^ (lr&15)) << 4) + (c&7)*2) = s4;
      *reinterpret_cast<unsigned*>(smem + L_H8 + lr*256 + ((g ^ (lr&15)) << 3) + (c&7)) = pack_fp8x4(sf);
      if (b16){
        *reinterpret_cast<bf4*>(o16 + obase) = s4;
        if (t == 1023) *reinterpret_cast<bf4*>(o16 + 16777216u + (size_t)(b0+lr)*256 + c) = s4;
      } else {
        *reinterpret_cast<f32x4*>(o32 + obase) = sf;
        if (t == 1023) *reinterpret_cast<f32x4*>(o32 + 16777216u + (size_t)(b0+lr)*256 + c) = sf;
      }
    }
    asm volatile("s_waitcnt lgkmcnt(0)" ::: "memory");
    __builtin_amdgcn_s_barrier();
    asm volatile("" ::: "memory");

    apt += 768; ept += 256; obase += 256;
  }
}

// ---------------------------------------------------------------- host
extern "C" void kernel_launch(void* const* d_in, const int* in_sizes, int n_in,
                              void* d_out, int out_size, void* d_ws, size_t ws_size,
                              hipStream_t stream)
{
  const void* x   = d_in[0];
  const void* h0  = d_in[1];
  const void* eps = d_in[2];
  const void* Wz  = d_in[3];
  const void* bz  = d_in[4];
  const void* Wr  = d_in[5];
  const void* br  = d_in[6];
  const void* Wtx = d_in[7];
  const void* btx = d_in[8];
  const void* Wth = d_in[9];
  const void* bth = d_in[10];
  const void* Wd  = d_in[11];
  const void* bd  = d_in[12];
  ushort_t* ws16 = (ushort_t*)d_ws;
  uint_t* flag = (uint_t*)((char*)d_ws + FLAG_BYTE);
  const ushort_t* aux = ws16 + AUX_OFF;
  unsigned char* f8w = (unsigned char*)d_ws + F8_OFF_BYTES;
  ushort_t* Ax = (ushort_t*)((char*)d_ws + AX_OFF_BYTES);
  ushort_t* eps16 = (ushort_t*)((char*)d_ws + EPS_OFF_BYTES);

  detect_kernel<<<dim3(1), dim3(64), 0, stream>>>((const uint_t*)x, flag);
  prep_kernel<<<dim3(2118), dim3(256), 0, stream>>>(Wz, Wr, Wtx, Wth, Wd,
                                                    bz, br, btx, bth, bd, h0,
                                                    flag, ws16);
  prep_f8_kernel<<<dim3(192), dim3(256), 0, stream>>>(ws16, f8w);
  epscvt_kernel<<<dim3(8192), dim3(256), 0, stream>>>(eps, flag, eps16);
  xproj_kernel<<<dim3(3072), dim3(256), 0, stream>>>(x, ws16, aux, flag, Ax);

  (void)hipFuncSetAttribute(reinterpret_cast<const void*>(&gru_kernel),
                            hipFuncAttributeMaxDynamicSharedMemorySize, SMEM_REC);
  gru_kernel<<<dim3(4), dim3(1024), SMEM_REC, stream>>>(ws16, f8w, Ax, eps16, flag, d_out);
}

// Round 10
// 5980.650 us; speedup vs baseline: 1.4244x; 1.0314x over previous
//
#include <hip/hip_runtime.h>
#include <hip/hip_bf16.h>

typedef unsigned short ushort_t;
typedef unsigned int uint_t;
typedef unsigned long long u64_t;
using f32x4 = __attribute__((ext_vector_type(4))) float;
using bf4 = __attribute__((ext_vector_type(4))) short;
using short8 = __attribute__((ext_vector_type(8))) short;

#define MFMA_B16(a,b,c) __builtin_amdgcn_mfma_f32_16x16x32_bf16((a),(b),(c),0,0,0)
#define MFMA_F8(a,b,c)  __builtin_amdgcn_mfma_f32_16x16x32_fp8_fp8((long)(a),(long)(b),(c),0,0,0)

static __device__ __forceinline__ float bf2f(ushort_t u){
  unsigned v = ((unsigned)u) << 16;
  return __builtin_bit_cast(float, v);
}
static __device__ __forceinline__ ushort_t f2bf(float f){
  __hip_bfloat16 h = __float2bfloat16(f);
  return __builtin_bit_cast(unsigned short, h);
}
static __device__ __forceinline__ f32x4 unpack4(bf4 v){
  f32x4 r;
  r[0]=bf2f((ushort_t)v[0]); r[1]=bf2f((ushort_t)v[1]);
  r[2]=bf2f((ushort_t)v[2]); r[3]=bf2f((ushort_t)v[3]);
  return r;
}
static __device__ __forceinline__ unsigned pack_fp8x4(f32x4 f){
  unsigned u = __builtin_amdgcn_cvt_pk_fp8_f32(f[0], f[1], 0, false);
  u = __builtin_amdgcn_cvt_pk_fp8_f32(f[2], f[3], u, true);
  return u;
}

// ws layout:
//   [0, 524288) elems  : bf16 weights, 2048 rows x 256 k (row-major)
//       rows 0-767: xproj B (Wzx^T|Wrx^T|Wtx^T); 768: Wzh^T; 1024: Wrh^T;
//       1280: Wth^T; 1536-2047: Wd^T (1536-1791 mean, 1792-2047 logvar)
//   [524288, 542208)   : bf16 aux (bz|br|btx|bth|bd|h0)
//   byte 1084416       : uint flag (1 = inputs bf16, 0 = f32)
//   byte 1088512       : fp8 weights: Wrh 64K | Wth 64K | Wd_lv 64K
//   byte 2 MB          : Ax bf16 (65536 x 768)
//   byte 112 MB        : eps bf16 (16777216)
#define W_ELEMS  524288
#define AUX_OFF  524288
#define AUX_BTH  768
#define AUX_BD   1024
#define AUX_H0   1536
#define FLAG_BYTE 1084416u
#define F8_OFF_BYTES  1088512u
#define AX_OFF_BYTES  (2u<<20)
#define EPS_OFF_BYTES (112u<<20)
#define ROW_ZH 768
#define ROW_RH 1024
#define ROW_TH 1280
#define ROW_D  1536

// gru LDS map (bytes)
#define L_WZ    0         // 256 rows x 512 B, swizzled (Wzh^T bf16)
#define L_H16   131072    // 16 x 512 B (h bf16)
#define L_HB16  139264    // 16 x 512 B (h_base bf16)
#define L_H8    147456    // 16 x 256 B (h fp8)
#define L_HB8   151552    // 16 x 256 B (h_base fp8)
#define L_BIAS  155648    // bth[256] | bd[512] bf16
#define SMEM_REC 157184

// ---------------------------------------------------------------- dtype detect
__global__ __launch_bounds__(64) void detect_kernel(const uint_t* __restrict__ x,
                                                    uint_t* __restrict__ flag)
{
  int l = threadIdx.x;
  int cnt = 0;
  for (int i = 0; i < 8; ++i){
    uint_t w = x[i*64 + l];
    uint_t e = (w >> 7) & 0xFF;
    unsigned long long m = __ballot(e >= 100 && e <= 136);
    if (l == 0) cnt += __popcll(m);
  }
  if (l == 0) *flag = (cnt >= 256) ? 1u : 0u;
}

// ---------------------------------------------------------------- prep (canonicalize to bf16)
__global__ __launch_bounds__(256) void prep_kernel(
    const void* __restrict__ Wz, const void* __restrict__ Wr,
    const void* __restrict__ Wtx, const void* __restrict__ Wth,
    const void* __restrict__ Wd,
    const void* __restrict__ bz, const void* __restrict__ br,
    const void* __restrict__ btx, const void* __restrict__ bth,
    const void* __restrict__ bd, const void* __restrict__ h0,
    const uint_t* __restrict__ flag, ushort_t* __restrict__ o)
{
  const bool b16 = (*flag != 0);
  int i = blockIdx.x * 256 + threadIdx.x;          // < 542208
  const void* src; int idx;
  if (i < W_ELEMS){
    int row = i >> 8, k = i & 255;
    if      (row <  256){ src = Wz;  idx = k*256 + row;         }
    else if (row <  512){ src = Wr;  idx = k*256 + (row-256);   }
    else if (row <  768){ src = Wtx; idx = k*256 + (row-512);   }
    else if (row < 1024){ src = Wz;  idx = (256+k)*256 + (row-768);  }
    else if (row < 1280){ src = Wr;  idx = (256+k)*256 + (row-1024); }
    else if (row < 1536){ src = Wth; idx = k*256 + (row-1280);  }
    else                { src = Wd;  idx = k*512 + (row-1536);  }
  } else {
    int j = i - W_ELEMS;
    if      (j <  256){ src = bz;  idx = j;       }
    else if (j <  512){ src = br;  idx = j-256;   }
    else if (j <  768){ src = btx; idx = j-512;   }
    else if (j < 1024){ src = bth; idx = j-768;   }
    else if (j < 1536){ src = bd;  idx = j-1024;  }
    else              { src = h0;  idx = j-1536;  }
  }
  o[i] = b16 ? ((const ushort_t*)src)[idx] : f2bf(((const float*)src)[idx]);
}

// ---------------------------------------------------------------- prep fp8 (Wrh|Wth|Wd_lv)
__global__ __launch_bounds__(256) void prep_f8_kernel(
    const ushort_t* __restrict__ ws, unsigned char* __restrict__ o)
{
  int i = blockIdx.x * 256 + threadIdx.x;          // < 49152, 4 elems each
  int m = i >> 14;                                 // region 0,1,2
  int b = (i & 16383) * 4;                         // byte offset in 64K region
  int row = b >> 8, k = b & 255;
  int srow = (m == 0) ? (ROW_RH + row) : (m == 1) ? (ROW_TH + row) : (ROW_D + 256 + row);
  f32x4 f = unpack4(*reinterpret_cast<const bf4*>(ws + srow*256 + k));
  *reinterpret_cast<unsigned*>(o + (size_t)i*4) = pack_fp8x4(f);
}

// ---------------------------------------------------------------- eps -> bf16
__global__ __launch_bounds__(256) void epscvt_kernel(
    const void* __restrict__ eps, const uint_t* __restrict__ flag,
    ushort_t* __restrict__ o)
{
  const bool b16 = (*flag != 0);
  int i = blockIdx.x * 256 + threadIdx.x;          // 8 elems each, 16777216 total
  if (b16){
    short8 v = reinterpret_cast<const short8*>(eps)[i];
    reinterpret_cast<short8*>(o)[i] = v;
  } else {
    const f32x4* e = reinterpret_cast<const f32x4*>(eps) + i*2;
    f32x4 a = e[0], b = e[1];
    short8 v;
    v[0]=(short)f2bf(a[0]); v[1]=(short)f2bf(a[1]); v[2]=(short)f2bf(a[2]); v[3]=(short)f2bf(a[3]);
    v[4]=(short)f2bf(b[0]); v[5]=(short)f2bf(b[1]); v[6]=(short)f2bf(b[2]); v[7]=(short)f2bf(b[3]);
    reinterpret_cast<short8*>(o)[i] = v;
  }
}

// ---------------------------------------------------------------- x projection GEMM
__global__ __launch_bounds__(256) void xproj_kernel(
    const void* __restrict__ x, const ushort_t* __restrict__ wsB,
    const ushort_t* __restrict__ aux, const uint_t* __restrict__ flag,
    ushort_t* __restrict__ Ax)
{
  __shared__ ushort_t As[32768];
  const bool b16 = (*flag != 0);
  const int tid = threadIdx.x, w = tid >> 6, l = tid & 63, lr = l & 15, lg = l >> 4;
  const int mt = blockIdx.x % 512, nb = blockIdx.x / 512;
  const int m0 = mt * 128, n0 = nb * 128;

  #pragma unroll
  for (int i = 0; i < 16; ++i){
    int gidx = i*256 + tid, row = gidx >> 5, g = gidx & 31;
    short8 v;
    if (b16){
      v = *reinterpret_cast<const short8*>((const ushort_t*)x + (m0+row)*256 + g*8);
    } else {
      const f32x4* xf = reinterpret_cast<const f32x4*>((const float*)x + (m0+row)*256 + g*8);
      f32x4 a0 = xf[0], a1 = xf[1];
      v[0]=(short)f2bf(a0[0]); v[1]=(short)f2bf(a0[1]); v[2]=(short)f2bf(a0[2]); v[3]=(short)f2bf(a0[3]);
      v[4]=(short)f2bf(a1[0]); v[5]=(short)f2bf(a1[1]); v[6]=(short)f2bf(a1[2]); v[7]=(short)f2bf(a1[3]);
    }
    *reinterpret_cast<short8*>(reinterpret_cast<char*>(As) + row*512 + ((g ^ (row&7)) << 4)) = v;
  }
  __syncthreads();

  const int wr = w >> 1, wc = w & 1;
  f32x4 acc[4][4];
  #pragma unroll
  for (int a = 0; a < 4; ++a)
    #pragma unroll
    for (int b = 0; b < 4; ++b) acc[a][b] = (f32x4){0.f,0.f,0.f,0.f};

  #pragma unroll
  for (int ks = 0; ks < 8; ++ks){
    short8 av[4], bv[4];
    #pragma unroll
    for (int mi = 0; mi < 4; ++mi){
      int rT = 64*wr + 16*mi + lr, g = ks*4 + lg;
      av[mi] = *reinterpret_cast<const short8*>(reinterpret_cast<const char*>(As) + rT*512 + ((g ^ (rT&7)) << 4));
    }
    #pragma unroll
    for (int ni = 0; ni < 4; ++ni){
      int nr = n0 + 64*wc + 16*ni + lr;
      bv[ni] = *reinterpret_cast<const short8*>(wsB + nr*256 + ks*32 + lg*8);
    }
    #pragma unroll
    for (int mi = 0; mi < 4; ++mi)
      #pragma unroll
      for (int ni = 0; ni < 4; ++ni)
        acc[mi][ni] = MFMA_B16(av[mi], bv[ni], acc[mi][ni]);
  }

  #pragma unroll
  for (int ni = 0; ni < 4; ++ni){
    int c = n0 + 64*wc + 16*ni + lr;
    float bias = bf2f(aux[c]);
    #pragma unroll
    for (int mi = 0; mi < 4; ++mi)
      #pragma unroll
      for (int j = 0; j < 4; ++j){
        int m = m0 + 64*wr + 16*mi + lg*4 + j;
        Ax[m*768 + c] = f2bf(acc[mi][ni][j] + bias);
      }
  }
}

// ---------------------------------------------------------------- recurrent kernel
// 4 WGs x 1024 threads (16 waves; __launch_bounds__(1024,1) -> 16 waves/CU
// = 4/SIMD -> 128 VGPR budget, the R3-proven CUDA-style mechanism).
// WG owns batch rows [16*bid,+16); wave w owns cols [16w, 16w+16).
// Operand-swapped MFMA: D = W(A) x h(B); lane holds
// (batch = lane&15, cols = 16w + (lane>>4)*4 + q).
// ALL weights resident: Wzh bf16 in LDS; Wrh/Wth/Wd_lv fp8 + Wd_mean bf16 in regs.
// Per-step VMEM = Ax (3xb64) + eps (1xb64).
__global__ void __launch_bounds__(1024, 1) gru_kernel(
    const ushort_t* __restrict__ ws16, const unsigned char* __restrict__ f8w,
    const ushort_t* __restrict__ Ax, const ushort_t* __restrict__ eps16,
    const uint_t* __restrict__ flag, void* __restrict__ outp)
{
  extern __shared__ char smem[];
  const bool b16 = (*flag != 0);
  ushort_t* o16 = (ushort_t*)outp;
  float*    o32 = (float*)outp;
  const ushort_t* aux = ws16 + AUX_OFF;
  ushort_t* bias_lds = (ushort_t*)(smem + L_BIAS);
  const int tid = threadIdx.x, w = tid >> 6, l = tid & 63, lr = l & 15, lg = l >> 4;
  const int b0 = blockIdx.x * 16;
  const int c0 = 16 * w;
  const int cl = c0 + lg*4;                 // lane's 4-col base

  // stage Wzh^T into LDS (swizzled, granule 16B, XOR row&15)
  for (int gi = tid; gi < 8192; gi += 1024){
    int row = gi >> 5, g = gi & 31;
    short8 v = *reinterpret_cast<const short8*>(ws16 + (ROW_ZH + row)*256 + g*8);
    *reinterpret_cast<short8*>(smem + row*512 + ((g ^ (row&15)) << 4)) = v;
  }
  if (tid < 256) bias_lds[tid] = aux[AUX_BTH + tid];
  if (tid < 512) bias_lds[256 + tid] = aux[AUX_BD + tid];

  // resident weight fragments (one 16-col tile per wave)
  const unsigned char* f_rh = f8w;
  const unsigned char* f_th = f8w + 65536;
  const unsigned char* f_dl = f8w + 131072;
  u64_t wrh8[8], wth8[8], wdl8[8];
  short8 wdm[8];
  {
    int r = c0 + lr;
    #pragma unroll
    for (int ks = 0; ks < 8; ++ks){
      wrh8[ks] = *reinterpret_cast<const u64_t*>(f_rh + r*256 + ks*32 + lg*8);
      wth8[ks] = *reinterpret_cast<const u64_t*>(f_th + r*256 + ks*32 + lg*8);
      wdl8[ks] = *reinterpret_cast<const u64_t*>(f_dl + r*256 + ks*32 + lg*8);
      wdm[ks]  = *reinterpret_cast<const short8*>(ws16 + (ROW_D + r)*256 + ks*32 + lg*8);
    }
  }

  // h in fp32 regs; lane holds (batch=lr, cols cl+q)
  f32x4 hreg;
  {
    int c = cl, g = c >> 3;
    hreg = unpack4(*reinterpret_cast<const bf4*>(aux + AUX_H0 + (b0+lr)*256 + c));
    bf4 hv;
    hv[0]=(short)f2bf(hreg[0]); hv[1]=(short)f2bf(hreg[1]);
    hv[2]=(short)f2bf(hreg[2]); hv[3]=(short)f2bf(hreg[3]);
    *reinterpret_cast<bf4*>(smem + L_H16 + lr*512 + ((g ^ (lr&15)) << 4) + (c&7)*2) = hv;
    *reinterpret_cast<unsigned*>(smem + L_H8 + lr*256 + ((g ^ (lr&15)) << 3) + (c&7)) = pack_fp8x4(hreg);
  }
  __syncthreads();

  const ushort_t* apt = Ax    + (size_t)(b0+lr)*1024*768 + cl;
  const ushort_t* ept = eps16 + (size_t)(b0+lr)*1024*256 + cl;
  size_t obase = (size_t)(b0+lr)*262144 + cl;

  for (int t = 0; t < 1024; ++t){
    // this step's global loads (4 x b64), issued up front, consumed late
    bf4 axzp = *reinterpret_cast<const bf4*>(apt);
    bf4 axrp = *reinterpret_cast<const bf4*>(apt + 256);
    bf4 axtp = *reinterpret_cast<const bf4*>(apt + 512);
    bf4 epsp = *reinterpret_cast<const bf4*>(ept);

    // ---- phase 1: z (bf16), r (fp8), h@Wth (fp8)
    f32x4 az = (f32x4){0.f,0.f,0.f,0.f};
    f32x4 ar = az;
    f32x4 at = unpack4(*reinterpret_cast<const bf4*>(bias_lds + cl));
    #pragma unroll
    for (int ks = 0; ks < 8; ++ks){
      const int g = ks*4 + lg;
      short8 hB = *reinterpret_cast<const short8*>(smem + L_H16 + lr*512 + ((g ^ (lr&15)) << 4));
      u64_t  h8 = *reinterpret_cast<const u64_t*>(smem + L_H8 + lr*256 + ((g ^ (lr&15)) << 3));
      int nc = c0 + lr;
      short8 wz = *reinterpret_cast<const short8*>(smem + nc*512 + ((g ^ (nc&15)) << 4));
      az = MFMA_B16(wz, hB, az);
      ar = MFMA_F8(wrh8[ks], h8, ar);
      at = MFMA_F8(wth8[ks], h8, at);
    }

    // activations -> h_base (bf16 + fp8 copies into LDS)
    {
      f32x4 axz = unpack4(axzp), axr = unpack4(axrp), axt = unpack4(axtp);
      f32x4 hb;
      bf4 hb4;
      #pragma unroll
      for (int q = 0; q < 4; ++q){
        float zp = az[q] + axz[q];
        float rp = ar[q] + axr[q];
        float zv = 1.f/(1.f + __expf(-zp));
        float rv = 1.f/(1.f + __expf(-rp));
        float tp = axt[q] + rv*at[q];
        float e2 = __expf(-2.f*fabsf(tp));
        float tv = (1.f - e2)/(1.f + e2);
        tv = (tp < 0.f) ? -tv : tv;
        hb[q] = zv*hreg[q] + (1.f - zv)*tv;
        hb4[q] = (short)f2bf(hb[q]);
      }
      int c = cl, g = c >> 3;
      *reinterpret_cast<bf4*>(smem + L_HB16 + lr*512 + ((g ^ (lr&15)) << 4) + (c&7)*2) = hb4;
      *reinterpret_cast<unsigned*>(smem + L_HB8 + lr*256 + ((g ^ (lr&15)) << 3) + (c&7)) = pack_fp8x4(hb);
    }
    asm volatile("s_waitcnt lgkmcnt(0)" ::: "memory");
    __builtin_amdgcn_s_barrier();
    asm volatile("" ::: "memory");

    // ---- phase 2: mean (bf16, wdm) + logvar (fp8, wdl8) — all resident
    f32x4 apm = unpack4(*reinterpret_cast<const bf4*>(bias_lds + 256 + cl));
    f32x4 apl = unpack4(*reinterpret_cast<const bf4*>(bias_lds + 512 + cl));
    #pragma unroll
    for (int ks = 0; ks < 8; ++ks){
      const int g = ks*4 + lg;
      short8 hbB = *reinterpret_cast<const short8*>(smem + L_HB16 + lr*512 + ((g ^ (lr&15)) << 4));
      u64_t  hb8 = *reinterpret_cast<const u64_t*>(smem + L_HB8 + lr*256 + ((g ^ (lr&15)) << 3));
      apm = MFMA_B16(wdm[ks], hbB, apm);
      apl = MFMA_F8(wdl8[ks], hb8, apl);
    }

    // ---- sample + write h
    {
      f32x4 epsv = unpack4(epsp);
      bf4 s4;
      f32x4 sf;
      #pragma unroll
      for (int q = 0; q < 4; ++q){
        float mean = fminf(fmaxf(apm[q], -1000.f), 1000.f);
        float lvv  = fminf(fmaxf(apl[q], -30.f),   30.f);
        float s = mean + __expf(0.5f*lvv)*epsv[q];
        hreg[q] = s;
        sf[q] = s;
        s4[q] = (short)f2bf(s);
      }
      int c = cl, g = c >> 3;
      *reinterpret_cast<bf4*>(smem + L_H16 + lr*512 + ((g ^ (lr&15)) << 4) + (c&7)*2) = s4;
      *reinterpret_cast<unsigned*>(smem + L_H8 + lr*256 + ((g ^ (lr&15)) << 3) + (c&7)) = pack_fp8x4(sf);
      if (b16){
        *reinterpret_cast<bf4*>(o16 + obase) = s4;
        if (t == 1023) *reinterpret_cast<bf4*>(o16 + 16777216u + (size_t)(b0+lr)*256 + c) = s4;
      } else {
        *reinterpret_cast<f32x4*>(o32 + obase) = sf;
        if (t == 1023) *reinterpret_cast<f32x4*>(o32 + 16777216u + (size_t)(b0+lr)*256 + c) = sf;
      }
    }
    asm volatile("s_waitcnt lgkmcnt(0)" ::: "memory");
    __builtin_amdgcn_s_barrier();
    asm volatile("" ::: "memory");

    apt += 768; ept += 256; obase += 256;
  }
}

// ---------------------------------------------------------------- host
extern "C" void kernel_launch(void* const* d_in, const int* in_sizes, int n_in,
                              void* d_out, int out_size, void* d_ws, size_t ws_size,
                              hipStream_t stream)
{
  const void* x   = d_in[0];
  const void* h0  = d_in[1];
  const void* eps = d_in[2];
  const void* Wz  = d_in[3];
  const void* bz  = d_in[4];
  const void* Wr  = d_in[5];
  const void* br  = d_in[6];
  const void* Wtx = d_in[7];
  const void* btx = d_in[8];
  const void* Wth = d_in[9];
  const void* bth = d_in[10];
  const void* Wd  = d_in[11];
  const void* bd  = d_in[12];
  ushort_t* ws16 = (ushort_t*)d_ws;
  uint_t* flag = (uint_t*)((char*)d_ws + FLAG_BYTE);
  const ushort_t* aux = ws16 + AUX_OFF;
  unsigned char* f8w = (unsigned char*)d_ws + F8_OFF_BYTES;
  ushort_t* Ax = (ushort_t*)((char*)d_ws + AX_OFF_BYTES);
  ushort_t* eps16 = (ushort_t*)((char*)d_ws + EPS_OFF_BYTES);

  detect_kernel<<<dim3(1), dim3(64), 0, stream>>>((const uint_t*)x, flag);
  prep_kernel<<<dim3(2118), dim3(256), 0, stream>>>(Wz, Wr, Wtx, Wth, Wd,
                                                    bz, br, btx, bth, bd, h0,
                                                    flag, ws16);
  prep_f8_kernel<<<dim3(192), dim3(256), 0, stream>>>(ws16, f8w);
  epscvt_kernel<<<dim3(8192), dim3(256), 0, stream>>>(eps, flag, eps16);
  xproj_kernel<<<dim3(3072), dim3(256), 0, stream>>>(x, ws16, aux, flag, Ax);

  (void)hipFuncSetAttribute(reinterpret_cast<const void*>(&gru_kernel),
                            hipFuncAttributeMaxDynamicSharedMemorySize, SMEM_REC);
  gru_kernel<<<dim3(4), dim3(1024), SMEM_REC, stream>>>(ws16, f8w, Ax, eps16, flag, d_out);
}

// Round 11
// 4561.477 us; speedup vs baseline: 1.8676x; 1.3111x over previous
//
#include <hip/hip_runtime.h>
#include <hip/hip_bf16.h>

typedef unsigned short ushort_t;
typedef unsigned int uint_t;
typedef unsigned long long u64_t;
using f32x4 = __attribute__((ext_vector_type(4))) float;
using bf4 = __attribute__((ext_vector_type(4))) short;
using short8 = __attribute__((ext_vector_type(8))) short;

#define MFMA_B16(a,b,c) __builtin_amdgcn_mfma_f32_16x16x32_bf16((a),(b),(c),0,0,0)
#define MFMA_F8(a,b,c)  __builtin_amdgcn_mfma_f32_16x16x32_fp8_fp8((long)(a),(long)(b),(c),0,0,0)

static __device__ __forceinline__ float bf2f(ushort_t u){
  unsigned v = ((unsigned)u) << 16;
  return __builtin_bit_cast(float, v);
}
static __device__ __forceinline__ ushort_t f2bf(float f){
  __hip_bfloat16 h = __float2bfloat16(f);
  return __builtin_bit_cast(unsigned short, h);
}
static __device__ __forceinline__ f32x4 unpack4(bf4 v){
  f32x4 r;
  r[0]=bf2f((ushort_t)v[0]); r[1]=bf2f((ushort_t)v[1]);
  r[2]=bf2f((ushort_t)v[2]); r[3]=bf2f((ushort_t)v[3]);
  return r;
}
static __device__ __forceinline__ unsigned pack_fp8x4(f32x4 f){
  unsigned u = __builtin_amdgcn_cvt_pk_fp8_f32(f[0], f[1], 0, false);
  u = __builtin_amdgcn_cvt_pk_fp8_f32(f[2], f[3], u, true);
  return u;
}

// ws layout:
//   [0, 524288) elems  : bf16 weights, 2048 rows x 256 k (row-major)
//       rows 0-767: xproj B (Wzx^T|Wrx^T|Wtx^T); 768: Wzh^T; 1024: Wrh^T;
//       1280: Wth^T; 1536-2047: Wd^T (1536-1791 mean, 1792-2047 logvar)
//   [524288, 542208)   : bf16 aux (bz|br|btx|bth|bd|h0)
//   byte 1084416       : uint flag (1 = inputs bf16, 0 = f32)
//   byte 1088512       : fp8 weights: Wrh 64K | Wth 64K | Wd_lv 64K
//   byte 2 MB          : Ax bf16 (65536 x 768)
//   byte 112 MB        : eps bf16 (16777216)
#define W_ELEMS  524288
#define AUX_OFF  524288
#define AUX_BTH  768
#define AUX_BD   1024
#define AUX_H0   1536
#define FLAG_BYTE 1084416u
#define F8_OFF_BYTES  1088512u
#define AX_OFF_BYTES  (2u<<20)
#define EPS_OFF_BYTES (112u<<20)
#define ROW_ZH 768
#define ROW_RH 1024
#define ROW_TH 1280
#define ROW_D  1536

// gru LDS map (bytes)
#define L_WZ    0         // 256 rows x 512 B, swizzled (Wzh^T bf16)
#define L_H16   131072    // 16 x 512 B (h bf16)
#define L_HB16  139264    // 16 x 512 B (h_base bf16)
#define L_H8    147456    // 16 x 256 B (h fp8)
#define L_HB8   151552    // 16 x 256 B (h_base fp8)
#define L_BIAS  155648    // bth[256] | bd[512] bf16
#define SMEM_REC 157184

// ---------------------------------------------------------------- dtype detect
__global__ __launch_bounds__(64) void detect_kernel(const uint_t* __restrict__ x,
                                                    uint_t* __restrict__ flag)
{
  int l = threadIdx.x;
  int cnt = 0;
  for (int i = 0; i < 8; ++i){
    uint_t w = x[i*64 + l];
    uint_t e = (w >> 7) & 0xFF;
    unsigned long long m = __ballot(e >= 100 && e <= 136);
    if (l == 0) cnt += __popcll(m);
  }
  if (l == 0) *flag = (cnt >= 256) ? 1u : 0u;
}

// ---------------------------------------------------------------- prep (canonicalize to bf16)
__global__ __launch_bounds__(256) void prep_kernel(
    const void* __restrict__ Wz, const void* __restrict__ Wr,
    const void* __restrict__ Wtx, const void* __restrict__ Wth,
    const void* __restrict__ Wd,
    const void* __restrict__ bz, const void* __restrict__ br,
    const void* __restrict__ btx, const void* __restrict__ bth,
    const void* __restrict__ bd, const void* __restrict__ h0,
    const uint_t* __restrict__ flag, ushort_t* __restrict__ o)
{
  const bool b16 = (*flag != 0);
  int i = blockIdx.x * 256 + threadIdx.x;          // < 542208
  const void* src; int idx;
  if (i < W_ELEMS){
    int row = i >> 8, k = i & 255;
    if      (row <  256){ src = Wz;  idx = k*256 + row;         }
    else if (row <  512){ src = Wr;  idx = k*256 + (row-256);   }
    else if (row <  768){ src = Wtx; idx = k*256 + (row-512);   }
    else if (row < 1024){ src = Wz;  idx = (256+k)*256 + (row-768);  }
    else if (row < 1280){ src = Wr;  idx = (256+k)*256 + (row-1024); }
    else if (row < 1536){ src = Wth; idx = k*256 + (row-1280);  }
    else                { src = Wd;  idx = k*512 + (row-1536);  }
  } else {
    int j = i - W_ELEMS;
    if      (j <  256){ src = bz;  idx = j;       }
    else if (j <  512){ src = br;  idx = j-256;   }
    else if (j <  768){ src = btx; idx = j-512;   }
    else if (j < 1024){ src = bth; idx = j-768;   }
    else if (j < 1536){ src = bd;  idx = j-1024;  }
    else              { src = h0;  idx = j-1536;  }
  }
  o[i] = b16 ? ((const ushort_t*)src)[idx] : f2bf(((const float*)src)[idx]);
}

// ---------------------------------------------------------------- prep fp8 (Wrh|Wth|Wd_lv)
__global__ __launch_bounds__(256) void prep_f8_kernel(
    const ushort_t* __restrict__ ws, unsigned char* __restrict__ o)
{
  int i = blockIdx.x * 256 + threadIdx.x;          // < 49152, 4 elems each
  int m = i >> 14;                                 // region 0,1,2
  int b = (i & 16383) * 4;                         // byte offset in 64K region
  int row = b >> 8, k = b & 255;
  int srow = (m == 0) ? (ROW_RH + row) : (m == 1) ? (ROW_TH + row) : (ROW_D + 256 + row);
  f32x4 f = unpack4(*reinterpret_cast<const bf4*>(ws + srow*256 + k));
  *reinterpret_cast<unsigned*>(o + (size_t)i*4) = pack_fp8x4(f);
}

// ---------------------------------------------------------------- eps -> bf16
__global__ __launch_bounds__(256) void epscvt_kernel(
    const void* __restrict__ eps, const uint_t* __restrict__ flag,
    ushort_t* __restrict__ o)
{
  const bool b16 = (*flag != 0);
  int i = blockIdx.x * 256 + threadIdx.x;          // 8 elems each, 16777216 total
  if (b16){
    short8 v = reinterpret_cast<const short8*>(eps)[i];
    reinterpret_cast<short8*>(o)[i] = v;
  } else {
    const f32x4* e = reinterpret_cast<const f32x4*>(eps) + i*2;
    f32x4 a = e[0], b = e[1];
    short8 v;
    v[0]=(short)f2bf(a[0]); v[1]=(short)f2bf(a[1]); v[2]=(short)f2bf(a[2]); v[3]=(short)f2bf(a[3]);
    v[4]=(short)f2bf(b[0]); v[5]=(short)f2bf(b[1]); v[6]=(short)f2bf(b[2]); v[7]=(short)f2bf(b[3]);
    reinterpret_cast<short8*>(o)[i] = v;
  }
}

// ---------------------------------------------------------------- x projection GEMM
__global__ __launch_bounds__(256) void xproj_kernel(
    const void* __restrict__ x, const ushort_t* __restrict__ wsB,
    const ushort_t* __restrict__ aux, const uint_t* __restrict__ flag,
    ushort_t* __restrict__ Ax)
{
  __shared__ ushort_t As[32768];
  const bool b16 = (*flag != 0);
  const int tid = threadIdx.x, w = tid >> 6, l = tid & 63, lr = l & 15, lg = l >> 4;
  const int mt = blockIdx.x % 512, nb = blockIdx.x / 512;
  const int m0 = mt * 128, n0 = nb * 128;

  #pragma unroll
  for (int i = 0; i < 16; ++i){
    int gidx = i*256 + tid, row = gidx >> 5, g = gidx & 31;
    short8 v;
    if (b16){
      v = *reinterpret_cast<const short8*>((const ushort_t*)x + (m0+row)*256 + g*8);
    } else {
      const f32x4* xf = reinterpret_cast<const f32x4*>((const float*)x + (m0+row)*256 + g*8);
      f32x4 a0 = xf[0], a1 = xf[1];
      v[0]=(short)f2bf(a0[0]); v[1]=(short)f2bf(a0[1]); v[2]=(short)f2bf(a0[2]); v[3]=(short)f2bf(a0[3]);
      v[4]=(short)f2bf(a1[0]); v[5]=(short)f2bf(a1[1]); v[6]=(short)f2bf(a1[2]); v[7]=(short)f2bf(a1[3]);
    }
    *reinterpret_cast<short8*>(reinterpret_cast<char*>(As) + row*512 + ((g ^ (row&7)) << 4)) = v;
  }
  __syncthreads();

  const int wr = w >> 1, wc = w & 1;
  f32x4 acc[4][4];
  #pragma unroll
  for (int a = 0; a < 4; ++a)
    #pragma unroll
    for (int b = 0; b < 4; ++b) acc[a][b] = (f32x4){0.f,0.f,0.f,0.f};

  #pragma unroll
  for (int ks = 0; ks < 8; ++ks){
    short8 av[4], bv[4];
    #pragma unroll
    for (int mi = 0; mi < 4; ++mi){
      int rT = 64*wr + 16*mi + lr, g = ks*4 + lg;
      av[mi] = *reinterpret_cast<const short8*>(reinterpret_cast<const char*>(As) + rT*512 + ((g ^ (rT&7)) << 4));
    }
    #pragma unroll
    for (int ni = 0; ni < 4; ++ni){
      int nr = n0 + 64*wc + 16*ni + lr;
      bv[ni] = *reinterpret_cast<const short8*>(wsB + nr*256 + ks*32 + lg*8);
    }
    #pragma unroll
    for (int mi = 0; mi < 4; ++mi)
      #pragma unroll
      for (int ni = 0; ni < 4; ++ni)
        acc[mi][ni] = MFMA_B16(av[mi], bv[ni], acc[mi][ni]);
  }

  #pragma unroll
  for (int ni = 0; ni < 4; ++ni){
    int c = n0 + 64*wc + 16*ni + lr;
    float bias = bf2f(aux[c]);
    #pragma unroll
    for (int mi = 0; mi < 4; ++mi)
      #pragma unroll
      for (int j = 0; j < 4; ++j){
        int m = m0 + 64*wr + 16*mi + lg*4 + j;
        Ax[m*768 + c] = f2bf(acc[mi][ni][j] + bias);
      }
  }
}

// ---------------------------------------------------------------- recurrent kernel
// 4 WGs x 512 threads; __launch_bounds__(512,1): 1 block/CU x 8 waves
// = 2 waves/SIMD -> 256-VGPR budget (LDS already limits to 1 block/CU,
// so zero occupancy cost). WG owns batch rows [16*bid,+16); wave w owns
// cols [32w, 32w+32). Operand-swapped MFMA: D = W(A) x h(B); lane holds
// (batch = lane&15, cols = 32w + 16nt + (lane>>4)*4 + q).
// ALL weights resident: Wzh bf16 in LDS; Wrh/Wth/Wd_lv fp8 + Wd_mean bf16 in regs.
// Per-step VMEM = Ax (6xb64) + eps (2xb64).
__global__ void __launch_bounds__(512, 1) gru_kernel(
    const ushort_t* __restrict__ ws16, const unsigned char* __restrict__ f8w,
    const ushort_t* __restrict__ Ax, const ushort_t* __restrict__ eps16,
    const uint_t* __restrict__ flag, void* __restrict__ outp)
{
  extern __shared__ char smem[];
  const bool b16 = (*flag != 0);
  ushort_t* o16 = (ushort_t*)outp;
  float*    o32 = (float*)outp;
  const ushort_t* aux = ws16 + AUX_OFF;
  ushort_t* bias_lds = (ushort_t*)(smem + L_BIAS);
  const int tid = threadIdx.x, w = tid >> 6, l = tid & 63, lr = l & 15, lg = l >> 4;
  const int b0 = blockIdx.x * 16;
  const int c0 = 32 * w;
  const int cl = c0 + lg*4;                 // lane's col base (nt=0)

  // stage Wzh^T into LDS (swizzled, granule 16B, XOR row&15)
  for (int gi = tid; gi < 8192; gi += 512){
    int row = gi >> 5, g = gi & 31;
    short8 v = *reinterpret_cast<const short8*>(ws16 + (ROW_ZH + row)*256 + g*8);
    *reinterpret_cast<short8*>(smem + row*512 + ((g ^ (row&15)) << 4)) = v;
  }
  if (tid < 256) bias_lds[tid] = aux[AUX_BTH + tid];
  if (tid < 512) bias_lds[256 + tid] = aux[AUX_BD + tid];

  // resident weight fragments
  const unsigned char* f_rh = f8w;
  const unsigned char* f_th = f8w + 65536;
  const unsigned char* f_dl = f8w + 131072;
  u64_t wrh8[2][8], wth8[2][8], wdl8[2][8];
  short8 wdm[2][8];
  #pragma unroll
  for (int nt = 0; nt < 2; ++nt){
    int r = c0 + 16*nt + lr;
    #pragma unroll
    for (int ks = 0; ks < 8; ++ks){
      wrh8[nt][ks] = *reinterpret_cast<const u64_t*>(f_rh + r*256 + ks*32 + lg*8);
      wth8[nt][ks] = *reinterpret_cast<const u64_t*>(f_th + r*256 + ks*32 + lg*8);
      wdl8[nt][ks] = *reinterpret_cast<const u64_t*>(f_dl + r*256 + ks*32 + lg*8);
      wdm[nt][ks]  = *reinterpret_cast<const short8*>(ws16 + (ROW_D + r)*256 + ks*32 + lg*8);
    }
  }

  // h in fp32 regs; lane holds (batch=lr, cols cl+16nt+q)
  f32x4 hreg[2];
  #pragma unroll
  for (int nt = 0; nt < 2; ++nt){
    int c = cl + 16*nt, g = c >> 3;
    hreg[nt] = unpack4(*reinterpret_cast<const bf4*>(aux + AUX_H0 + (b0+lr)*256 + c));
    bf4 hv;
    hv[0]=(short)f2bf(hreg[nt][0]); hv[1]=(short)f2bf(hreg[nt][1]);
    hv[2]=(short)f2bf(hreg[nt][2]); hv[3]=(short)f2bf(hreg[nt][3]);
    *reinterpret_cast<bf4*>(smem + L_H16 + lr*512 + ((g ^ (lr&15)) << 4) + (c&7)*2) = hv;
    *reinterpret_cast<unsigned*>(smem + L_H8 + lr*256 + ((g ^ (lr&15)) << 3) + (c&7)) = pack_fp8x4(hreg[nt]);
  }
  __syncthreads();

  const ushort_t* apt = Ax    + (size_t)(b0+lr)*1024*768 + cl;
  const ushort_t* ept = eps16 + (size_t)(b0+lr)*1024*256 + cl;
  size_t obase = (size_t)(b0+lr)*262144 + cl;

  for (int t = 0; t < 1024; ++t){
    // this step's global loads (8 x b64), issued up front, consumed late
    bf4 axzp[2], axrp[2], axtp[2], epsp[2];
    #pragma unroll
    for (int nt = 0; nt < 2; ++nt){
      axzp[nt] = *reinterpret_cast<const bf4*>(apt + 16*nt);
      axrp[nt] = *reinterpret_cast<const bf4*>(apt + 256 + 16*nt);
      axtp[nt] = *reinterpret_cast<const bf4*>(apt + 512 + 16*nt);
      epsp[nt] = *reinterpret_cast<const bf4*>(ept + 16*nt);
    }

    // ---- phase 1: z (bf16), r (fp8), h@Wth (fp8)
    f32x4 az[2], ar[2], at[2];
    az[0] = (f32x4){0.f,0.f,0.f,0.f}; az[1] = az[0];
    ar[0] = az[0]; ar[1] = az[0];
    at[0] = unpack4(*reinterpret_cast<const bf4*>(bias_lds + cl));
    at[1] = unpack4(*reinterpret_cast<const bf4*>(bias_lds + cl + 16));
    #pragma unroll
    for (int ks = 0; ks < 8; ++ks){
      const int g = ks*4 + lg;
      short8 hB = *reinterpret_cast<const short8*>(smem + L_H16 + lr*512 + ((g ^ (lr&15)) << 4));
      u64_t  h8 = *reinterpret_cast<const u64_t*>(smem + L_H8 + lr*256 + ((g ^ (lr&15)) << 3));
      int nc0 = c0 + lr, nc1 = c0 + 16 + lr;
      short8 wz0 = *reinterpret_cast<const short8*>(smem + nc0*512 + ((g ^ (nc0&15)) << 4));
      short8 wz1 = *reinterpret_cast<const short8*>(smem + nc1*512 + ((g ^ (nc1&15)) << 4));
      az[0] = MFMA_B16(wz0, hB, az[0]);        az[1] = MFMA_B16(wz1, hB, az[1]);
      ar[0] = MFMA_F8(wrh8[0][ks], h8, ar[0]); ar[1] = MFMA_F8(wrh8[1][ks], h8, ar[1]);
      at[0] = MFMA_F8(wth8[0][ks], h8, at[0]); at[1] = MFMA_F8(wth8[1][ks], h8, at[1]);
    }

    // activations -> h_base (bf16 + fp8 copies into LDS)
    #pragma unroll
    for (int nt = 0; nt < 2; ++nt){
      f32x4 axz = unpack4(axzp[nt]), axr = unpack4(axrp[nt]), axt = unpack4(axtp[nt]);
      f32x4 hb;
      bf4 hb4;
      #pragma unroll
      for (int q = 0; q < 4; ++q){
        float zp = az[nt][q] + axz[q];
        float rp = ar[nt][q] + axr[q];
        float zv = 1.f/(1.f + __expf(-zp));
        float rv = 1.f/(1.f + __expf(-rp));
        float tp = axt[q] + rv*at[nt][q];
        float e2 = __expf(-2.f*fabsf(tp));
        float tv = (1.f - e2)/(1.f + e2);
        tv = (tp < 0.f) ? -tv : tv;
        hb[q] = zv*hreg[nt][q] + (1.f - zv)*tv;
        hb4[q] = (short)f2bf(hb[q]);
      }
      int c = cl + 16*nt, g = c >> 3;
      *reinterpret_cast<bf4*>(smem + L_HB16 + lr*512 + ((g ^ (lr&15)) << 4) + (c&7)*2) = hb4;
      *reinterpret_cast<unsigned*>(smem + L_HB8 + lr*256 + ((g ^ (lr&15)) << 3) + (c&7)) = pack_fp8x4(hb);
    }
    asm volatile("s_waitcnt lgkmcnt(0)" ::: "memory");
    __builtin_amdgcn_s_barrier();
    asm volatile("" ::: "memory");

    // ---- phase 2: mean (bf16, wdm) + logvar (fp8, wdl8) — all resident
    f32x4 apm[2], apl[2];
    apm[0] = unpack4(*reinterpret_cast<const bf4*>(bias_lds + 256 + cl));
    apm[1] = unpack4(*reinterpret_cast<const bf4*>(bias_lds + 256 + cl + 16));
    apl[0] = unpack4(*reinterpret_cast<const bf4*>(bias_lds + 512 + cl));
    apl[1] = unpack4(*reinterpret_cast<const bf4*>(bias_lds + 512 + cl + 16));
    #pragma unroll
    for (int ks = 0; ks < 8; ++ks){
      const int g = ks*4 + lg;
      short8 hbB = *reinterpret_cast<const short8*>(smem + L_HB16 + lr*512 + ((g ^ (lr&15)) << 4));
      u64_t  hb8 = *reinterpret_cast<const u64_t*>(smem + L_HB8 + lr*256 + ((g ^ (lr&15)) << 3));
      apm[0] = MFMA_B16(wdm[0][ks], hbB, apm[0]); apm[1] = MFMA_B16(wdm[1][ks], hbB, apm[1]);
      apl[0] = MFMA_F8(wdl8[0][ks], hb8, apl[0]); apl[1] = MFMA_F8(wdl8[1][ks], hb8, apl[1]);
    }

    // ---- sample + write h
    #pragma unroll
    for (int nt = 0; nt < 2; ++nt){
      f32x4 epsv = unpack4(epsp[nt]);
      bf4 s4;
      f32x4 sf;
      #pragma unroll
      for (int q = 0; q < 4; ++q){
        float mean = fminf(fmaxf(apm[nt][q], -1000.f), 1000.f);
        float lvv  = fminf(fmaxf(apl[nt][q], -30.f),   30.f);
        float s = mean + __expf(0.5f*lvv)*epsv[q];
        hreg[nt][q] = s;
        sf[q] = s;
        s4[q] = (short)f2bf(s);
      }
      int c = cl + 16*nt, g = c >> 3;
      *reinterpret_cast<bf4*>(smem + L_H16 + lr*512 + ((g ^ (lr&15)) << 4) + (c&7)*2) = s4;
      *reinterpret_cast<unsigned*>(smem + L_H8 + lr*256 + ((g ^ (lr&15)) << 3) + (c&7)) = pack_fp8x4(sf);
      size_t oi = obase + 16*nt;
      if (b16){
        *reinterpret_cast<bf4*>(o16 + oi) = s4;
        if (t == 1023) *reinterpret_cast<bf4*>(o16 + 16777216u + (size_t)(b0+lr)*256 + c) = s4;
      } else {
        *reinterpret_cast<f32x4*>(o32 + oi) = sf;
        if (t == 1023) *reinterpret_cast<f32x4*>(o32 + 16777216u + (size_t)(b0+lr)*256 + c) = sf;
      }
    }
    asm volatile("s_waitcnt lgkmcnt(0)" ::: "memory");
    __builtin_amdgcn_s_barrier();
    asm volatile("" ::: "memory");

    apt += 768; ept += 256; obase += 256;
  }
}

// ---------------------------------------------------------------- host
extern "C" void kernel_launch(void* const* d_in, const int* in_sizes, int n_in,
                              void* d_out, int out_size, void* d_ws, size_t ws_size,
                              hipStream_t stream)
{
  const void* x   = d_in[0];
  const void* h0  = d_in[1];
  const void* eps = d_in[2];
  const void* Wz  = d_in[3];
  const void* bz  = d_in[4];
  const void* Wr  = d_in[5];
  const void* br  = d_in[6];
  const void* Wtx = d_in[7];
  const void* btx = d_in[8];
  const void* Wth = d_in[9];
  const void* bth = d_in[10];
  const void* Wd  = d_in[11];
  const void* bd  = d_in[12];
  ushort_t* ws16 = (ushort_t*)d_ws;
  uint_t* flag = (uint_t*)((char*)d_ws + FLAG_BYTE);
  const ushort_t* aux = ws16 + AUX_OFF;
  unsigned char* f8w = (unsigned char*)d_ws + F8_OFF_BYTES;
  ushort_t* Ax = (ushort_t*)((char*)d_ws + AX_OFF_BYTES);
  ushort_t* eps16 = (ushort_t*)((char*)d_ws + EPS_OFF_BYTES);

  detect_kernel<<<dim3(1), dim3(64), 0, stream>>>((const uint_t*)x, flag);
  prep_kernel<<<dim3(2118), dim3(256), 0, stream>>>(Wz, Wr, Wtx, Wth, Wd,
                                                    bz, br, btx, bth, bd, h0,
                                                    flag, ws16);
  prep_f8_kernel<<<dim3(192), dim3(256), 0, stream>>>(ws16, f8w);
  epscvt_kernel<<<dim3(8192), dim3(256), 0, stream>>>(eps, flag, eps16);
  xproj_kernel<<<dim3(3072), dim3(256), 0, stream>>>(x, ws16, aux, flag, Ax);

  (void)hipFuncSetAttribute(reinterpret_cast<const void*>(&gru_kernel),
                            hipFuncAttributeMaxDynamicSharedMemorySize, SMEM_REC);
  gru_kernel<<<dim3(4), dim3(512), SMEM_REC, stream>>>(ws16, f8w, Ax, eps16, flag, d_out);
}

// Round 12
// 3996.143 us; speedup vs baseline: 2.1318x; 1.1415x over previous
//
#include <hip/hip_runtime.h>
#include <hip/hip_bf16.h>

typedef unsigned short ushort_t;
typedef unsigned int uint_t;
typedef unsigned long long u64_t;
using f32x4 = __attribute__((ext_vector_type(4))) float;
using bf4 = __attribute__((ext_vector_type(4))) short;
using short8 = __attribute__((ext_vector_type(8))) short;

#define MFMA_B16(a,b,c) __builtin_amdgcn_mfma_f32_16x16x32_bf16((a),(b),(c),0,0,0)
#define MFMA_F8(a,b,c)  __builtin_amdgcn_mfma_f32_16x16x32_fp8_fp8((long)(a),(long)(b),(c),0,0,0)

static __device__ __forceinline__ float bf2f(ushort_t u){
  unsigned v = ((unsigned)u) << 16;
  return __builtin_bit_cast(float, v);
}
static __device__ __forceinline__ ushort_t f2bf(float f){
  __hip_bfloat16 h = __float2bfloat16(f);
  return __builtin_bit_cast(unsigned short, h);
}
static __device__ __forceinline__ f32x4 unpack4(bf4 v){
  f32x4 r;
  r[0]=bf2f((ushort_t)v[0]); r[1]=bf2f((ushort_t)v[1]);
  r[2]=bf2f((ushort_t)v[2]); r[3]=bf2f((ushort_t)v[3]);
  return r;
}
static __device__ __forceinline__ unsigned pack_fp8x4(f32x4 f){
  unsigned u = __builtin_amdgcn_cvt_pk_fp8_f32(f[0], f[1], 0, false);
  u = __builtin_amdgcn_cvt_pk_fp8_f32(f[2], f[3], u, true);
  return u;
}
// reciprocal with one Newton step: rel err ~2^-28 (numerically = exact div here)
static __device__ __forceinline__ float rcp_nr(float x){
  float r = __builtin_amdgcn_rcpf(x);
  return r * (2.f - x*r);
}

// ws layout:
//   [0, 524288) elems  : bf16 weights, 2048 rows x 256 k (row-major)
//       rows 0-767: xproj B (Wzx^T|Wrx^T|Wtx^T); 768: Wzh^T; 1024: Wrh^T;
//       1280: Wth^T; 1536-2047: Wd^T (1536-1791 mean, 1792-2047 logvar)
//   [524288, 542208)   : bf16 aux (bz|br|btx|bth|bd|h0)
//   byte 1084416       : uint flag (1 = inputs bf16, 0 = f32)
//   byte 1088512       : fp8 weights: Wrh 64K | Wth 64K | Wd_lv 64K
//   byte 2 MB          : Ax bf16 (65536 x 768)
//   byte 112 MB        : eps bf16 (16777216)
#define W_ELEMS  524288
#define AUX_OFF  524288
#define AUX_BTH  768
#define AUX_BD   1024
#define AUX_H0   1536
#define FLAG_BYTE 1084416u
#define F8_OFF_BYTES  1088512u
#define AX_OFF_BYTES  (2u<<20)
#define EPS_OFF_BYTES (112u<<20)
#define ROW_ZH 768
#define ROW_RH 1024
#define ROW_TH 1280
#define ROW_D  1536

// gru LDS map (bytes). Linear-padded rows: bf16 stride 528 (132 dwords = 4 mod
// 32 -> lanes at lr*4 banks, 2-way b128 = free; 16B aligned), fp8 stride 264
// (66 dwords = 2 mod 32 -> conflict-free; 8B aligned). k-loop reads become
// base + ks*imm -> ds_read offset immediates, no per-access address math.
#define L_WZ    0         // 256 x 528 (Wzh^T bf16)
#define L_H16   135168    // 16 x 528 (h bf16)
#define L_HB16  143616    // 16 x 528 (h_base bf16)
#define L_H8    152064    // 16 x 264 (h fp8)
#define L_HB8   156288    // 16 x 264 (h_base fp8)
#define L_BIAS  160512    // bth[256] | bd[512] bf16
#define SMEM_REC 162048

// ---------------------------------------------------------------- dtype detect
__global__ __launch_bounds__(64) void detect_kernel(const uint_t* __restrict__ x,
                                                    uint_t* __restrict__ flag)
{
  int l = threadIdx.x;
  int cnt = 0;
  for (int i = 0; i < 8; ++i){
    uint_t w = x[i*64 + l];
    uint_t e = (w >> 7) & 0xFF;
    unsigned long long m = __ballot(e >= 100 && e <= 136);
    if (l == 0) cnt += __popcll(m);
  }
  if (l == 0) *flag = (cnt >= 256) ? 1u : 0u;
}

// ---------------------------------------------------------------- prep (canonicalize to bf16)
__global__ __launch_bounds__(256) void prep_kernel(
    const void* __restrict__ Wz, const void* __restrict__ Wr,
    const void* __restrict__ Wtx, const void* __restrict__ Wth,
    const void* __restrict__ Wd,
    const void* __restrict__ bz, const void* __restrict__ br,
    const void* __restrict__ btx, const void* __restrict__ bth,
    const void* __restrict__ bd, const void* __restrict__ h0,
    const uint_t* __restrict__ flag, ushort_t* __restrict__ o)
{
  const bool b16 = (*flag != 0);
  int i = blockIdx.x * 256 + threadIdx.x;          // < 542208
  const void* src; int idx;
  if (i < W_ELEMS){
    int row = i >> 8, k = i & 255;
    if      (row <  256){ src = Wz;  idx = k*256 + row;         }
    else if (row <  512){ src = Wr;  idx = k*256 + (row-256);   }
    else if (row <  768){ src = Wtx; idx = k*256 + (row-512);   }
    else if (row < 1024){ src = Wz;  idx = (256+k)*256 + (row-768);  }
    else if (row < 1280){ src = Wr;  idx = (256+k)*256 + (row-1024); }
    else if (row < 1536){ src = Wth; idx = k*256 + (row-1280);  }
    else                { src = Wd;  idx = k*512 + (row-1536);  }
  } else {
    int j = i - W_ELEMS;
    if      (j <  256){ src = bz;  idx = j;       }
    else if (j <  512){ src = br;  idx = j-256;   }
    else if (j <  768){ src = btx; idx = j-512;   }
    else if (j < 1024){ src = bth; idx = j-768;   }
    else if (j < 1536){ src = bd;  idx = j-1024;  }
    else              { src = h0;  idx = j-1536;  }
  }
  o[i] = b16 ? ((const ushort_t*)src)[idx] : f2bf(((const float*)src)[idx]);
}

// ---------------------------------------------------------------- prep fp8 (Wrh|Wth|Wd_lv)
__global__ __launch_bounds__(256) void prep_f8_kernel(
    const ushort_t* __restrict__ ws, unsigned char* __restrict__ o)
{
  int i = blockIdx.x * 256 + threadIdx.x;          // < 49152, 4 elems each
  int m = i >> 14;                                 // region 0,1,2
  int b = (i & 16383) * 4;                         // byte offset in 64K region
  int row = b >> 8, k = b & 255;
  int srow = (m == 0) ? (ROW_RH + row) : (m == 1) ? (ROW_TH + row) : (ROW_D + 256 + row);
  f32x4 f = unpack4(*reinterpret_cast<const bf4*>(ws + srow*256 + k));
  *reinterpret_cast<unsigned*>(o + (size_t)i*4) = pack_fp8x4(f);
}

// ---------------------------------------------------------------- eps -> bf16
__global__ __launch_bounds__(256) void epscvt_kernel(
    const void* __restrict__ eps, const uint_t* __restrict__ flag,
    ushort_t* __restrict__ o)
{
  const bool b16 = (*flag != 0);
  int i = blockIdx.x * 256 + threadIdx.x;          // 8 elems each, 16777216 total
  if (b16){
    short8 v = reinterpret_cast<const short8*>(eps)[i];
    reinterpret_cast<short8*>(o)[i] = v;
  } else {
    const f32x4* e = reinterpret_cast<const f32x4*>(eps) + i*2;
    f32x4 a = e[0], b = e[1];
    short8 v;
    v[0]=(short)f2bf(a[0]); v[1]=(short)f2bf(a[1]); v[2]=(short)f2bf(a[2]); v[3]=(short)f2bf(a[3]);
    v[4]=(short)f2bf(b[0]); v[5]=(short)f2bf(b[1]); v[6]=(short)f2bf(b[2]); v[7]=(short)f2bf(b[3]);
    reinterpret_cast<short8*>(o)[i] = v;
  }
}

// ---------------------------------------------------------------- x projection GEMM
__global__ __launch_bounds__(256) void xproj_kernel(
    const void* __restrict__ x, const ushort_t* __restrict__ wsB,
    const ushort_t* __restrict__ aux, const uint_t* __restrict__ flag,
    ushort_t* __restrict__ Ax)
{
  __shared__ ushort_t As[32768];
  const bool b16 = (*flag != 0);
  const int tid = threadIdx.x, w = tid >> 6, l = tid & 63, lr = l & 15, lg = l >> 4;
  const int mt = blockIdx.x % 512, nb = blockIdx.x / 512;
  const int m0 = mt * 128, n0 = nb * 128;

  #pragma unroll
  for (int i = 0; i < 16; ++i){
    int gidx = i*256 + tid, row = gidx >> 5, g = gidx & 31;
    short8 v;
    if (b16){
      v = *reinterpret_cast<const short8*>((const ushort_t*)x + (m0+row)*256 + g*8);
    } else {
      const f32x4* xf = reinterpret_cast<const f32x4*>((const float*)x + (m0+row)*256 + g*8);
      f32x4 a0 = xf[0], a1 = xf[1];
      v[0]=(short)f2bf(a0[0]); v[1]=(short)f2bf(a0[1]); v[2]=(short)f2bf(a0[2]); v[3]=(short)f2bf(a0[3]);
      v[4]=(short)f2bf(a1[0]); v[5]=(short)f2bf(a1[1]); v[6]=(short)f2bf(a1[2]); v[7]=(short)f2bf(a1[3]);
    }
    *reinterpret_cast<short8*>(reinterpret_cast<char*>(As) + row*512 + ((g ^ (row&7)) << 4)) = v;
  }
  __syncthreads();

  const int wr = w >> 1, wc = w & 1;
  f32x4 acc[4][4];
  #pragma unroll
  for (int a = 0; a < 4; ++a)
    #pragma unroll
    for (int b = 0; b < 4; ++b) acc[a][b] = (f32x4){0.f,0.f,0.f,0.f};

  #pragma unroll
  for (int ks = 0; ks < 8; ++ks){
    short8 av[4], bv[4];
    #pragma unroll
    for (int mi = 0; mi < 4; ++mi){
      int rT = 64*wr + 16*mi + lr, g = ks*4 + lg;
      av[mi] = *reinterpret_cast<const short8*>(reinterpret_cast<const char*>(As) + rT*512 + ((g ^ (rT&7)) << 4));
    }
    #pragma unroll
    for (int ni = 0; ni < 4; ++ni){
      int nr = n0 + 64*wc + 16*ni + lr;
      bv[ni] = *reinterpret_cast<const short8*>(wsB + nr*256 + ks*32 + lg*8);
    }
    #pragma unroll
    for (int mi = 0; mi < 4; ++mi)
      #pragma unroll
      for (int ni = 0; ni < 4; ++ni)
        acc[mi][ni] = MFMA_B16(av[mi], bv[ni], acc[mi][ni]);
  }

  #pragma unroll
  for (int ni = 0; ni < 4; ++ni){
    int c = n0 + 64*wc + 16*ni + lr;
    float bias = bf2f(aux[c]);
    #pragma unroll
    for (int mi = 0; mi < 4; ++mi)
      #pragma unroll
      for (int j = 0; j < 4; ++j){
        int m = m0 + 64*wr + 16*mi + lg*4 + j;
        Ax[m*768 + c] = f2bf(acc[mi][ni][j] + bias);
      }
  }
}

// ---------------------------------------------------------------- recurrent kernel
// 4 WGs x 512 threads (8 waves, 2/SIMD, 128-VGPR budget). WG owns batch rows
// [16*bid,+16); wave w owns cols [32w,32w+32). Operand-swapped MFMA:
// D = W(A) x h(B); lane holds (batch=lane&15, cols = 32w+16nt+(lane>>4)*4+q).
// ALL weights resident: Wzh bf16 in LDS; Wrh/Wth/Wd_lv fp8 + Wd_mean bf16 in
// regs. Per-step VMEM = Ax (6xb64) + eps (2xb64). LDS addressing is linear:
// per-stream base VGPR + ks*64/ks*32 immediate ds offsets (no swizzle math).
__global__ void __launch_bounds__(512, 1) gru_kernel(
    const ushort_t* __restrict__ ws16, const unsigned char* __restrict__ f8w,
    const ushort_t* __restrict__ Ax, const ushort_t* __restrict__ eps16,
    const uint_t* __restrict__ flag, void* __restrict__ outp)
{
  extern __shared__ char smem[];
  const bool b16 = (*flag != 0);
  ushort_t* o16 = (ushort_t*)outp;
  float*    o32 = (float*)outp;
  const ushort_t* aux = ws16 + AUX_OFF;
  ushort_t* bias_lds = (ushort_t*)(smem + L_BIAS);
  const int tid = threadIdx.x, w = tid >> 6, l = tid & 63, lr = l & 15, lg = l >> 4;
  const int b0 = blockIdx.x * 16;
  const int c0 = 32 * w;
  const int cl = c0 + lg*4;                 // lane's col base (nt=0)

  // stage Wzh^T into LDS (linear, 528 B row stride)
  for (int gi = tid; gi < 8192; gi += 512){
    int row = gi >> 5, g = gi & 31;
    short8 v = *reinterpret_cast<const short8*>(ws16 + (ROW_ZH + row)*256 + g*8);
    *reinterpret_cast<short8*>(smem + row*528 + g*16) = v;
  }
  if (tid < 256) bias_lds[tid] = aux[AUX_BTH + tid];
  if (tid < 512) bias_lds[256 + tid] = aux[AUX_BD + tid];

  // resident weight fragments
  const unsigned char* f_rh = f8w;
  const unsigned char* f_th = f8w + 65536;
  const unsigned char* f_dl = f8w + 131072;
  u64_t wrh8[2][8], wth8[2][8], wdl8[2][8];
  short8 wdm[2][8];
  #pragma unroll
  for (int nt = 0; nt < 2; ++nt){
    int r = c0 + 16*nt + lr;
    #pragma unroll
    for (int ks = 0; ks < 8; ++ks){
      wrh8[nt][ks] = *reinterpret_cast<const u64_t*>(f_rh + r*256 + ks*32 + lg*8);
      wth8[nt][ks] = *reinterpret_cast<const u64_t*>(f_th + r*256 + ks*32 + lg*8);
      wdl8[nt][ks] = *reinterpret_cast<const u64_t*>(f_dl + r*256 + ks*32 + lg*8);
      wdm[nt][ks]  = *reinterpret_cast<const short8*>(ws16 + (ROW_D + r)*256 + ks*32 + lg*8);
    }
  }

  // per-lane LDS stream bases (t-invariant)
  const int wzr0 = L_WZ + (c0 + lr)*528 + lg*16;
  const int wzr1 = L_WZ + (c0 + 16 + lr)*528 + lg*16;
  const int h16r = L_H16 + lr*528 + lg*16;
  const int hb16r= L_HB16+ lr*528 + lg*16;
  const int h8r  = L_H8  + lr*264 + lg*8;
  const int hb8r = L_HB8 + lr*264 + lg*8;
  const int h16w = L_H16 + lr*528 + cl*2;
  const int hb16w= L_HB16+ lr*528 + cl*2;
  const int h8w  = L_H8  + lr*264 + cl;
  const int hb8w = L_HB8 + lr*264 + cl;

  // h in fp32 regs; lane holds (batch=lr, cols cl+16nt+q)
  f32x4 hreg[2];
  #pragma unroll
  for (int nt = 0; nt < 2; ++nt){
    int c = cl + 16*nt;
    hreg[nt] = unpack4(*reinterpret_cast<const bf4*>(aux + AUX_H0 + (b0+lr)*256 + c));
    bf4 hv;
    hv[0]=(short)f2bf(hreg[nt][0]); hv[1]=(short)f2bf(hreg[nt][1]);
    hv[2]=(short)f2bf(hreg[nt][2]); hv[3]=(short)f2bf(hreg[nt][3]);
    *reinterpret_cast<bf4*>(smem + h16w + nt*32) = hv;
    *reinterpret_cast<unsigned*>(smem + h8w + nt*16) = pack_fp8x4(hreg[nt]);
  }
  __syncthreads();

  const ushort_t* apt = Ax    + (size_t)(b0+lr)*1024*768 + cl;
  const ushort_t* ept = eps16 + (size_t)(b0+lr)*1024*256 + cl;
  size_t obase = (size_t)(b0+lr)*262144 + cl;

  for (int t = 0; t < 1024; ++t){
    // this step's global loads (8 x b64), issued up front, consumed late
    bf4 axzp[2], axrp[2], axtp[2], epsp[2];
    #pragma unroll
    for (int nt = 0; nt < 2; ++nt){
      axzp[nt] = *reinterpret_cast<const bf4*>(apt + 16*nt);
      axrp[nt] = *reinterpret_cast<const bf4*>(apt + 256 + 16*nt);
      axtp[nt] = *reinterpret_cast<const bf4*>(apt + 512 + 16*nt);
      epsp[nt] = *reinterpret_cast<const bf4*>(ept + 16*nt);
    }

    // ---- phase 1: z (bf16), r (fp8), h@Wth (fp8)
    f32x4 az[2], ar[2], at[2];
    az[0] = (f32x4){0.f,0.f,0.f,0.f}; az[1] = az[0];
    ar[0] = az[0]; ar[1] = az[0];
    at[0] = unpack4(*reinterpret_cast<const bf4*>(bias_lds + cl));
    at[1] = unpack4(*reinterpret_cast<const bf4*>(bias_lds + cl + 16));
    #pragma unroll
    for (int ks = 0; ks < 8; ++ks){
      short8 hB = *reinterpret_cast<const short8*>(smem + h16r + ks*64);
      u64_t  h8 = *reinterpret_cast<const u64_t*>(smem + h8r + ks*32);
      short8 wz0 = *reinterpret_cast<const short8*>(smem + wzr0 + ks*64);
      short8 wz1 = *reinterpret_cast<const short8*>(smem + wzr1 + ks*64);
      az[0] = MFMA_B16(wz0, hB, az[0]);        az[1] = MFMA_B16(wz1, hB, az[1]);
      ar[0] = MFMA_F8(wrh8[0][ks], h8, ar[0]); ar[1] = MFMA_F8(wrh8[1][ks], h8, ar[1]);
      at[0] = MFMA_F8(wth8[0][ks], h8, at[0]); at[1] = MFMA_F8(wth8[1][ks], h8, at[1]);
    }

    // activations -> h_base (bf16 + fp8 copies into LDS)
    #pragma unroll
    for (int nt = 0; nt < 2; ++nt){
      f32x4 axz = unpack4(axzp[nt]), axr = unpack4(axrp[nt]), axt = unpack4(axtp[nt]);
      f32x4 hb;
      bf4 hb4;
      #pragma unroll
      for (int q = 0; q < 4; ++q){
        float zp = az[nt][q] + axz[q];
        float rp = ar[nt][q] + axr[q];
        float zv = rcp_nr(1.f + __expf(-zp));
        float rv = rcp_nr(1.f + __expf(-rp));
        float tp = axt[q] + rv*at[nt][q];
        float e2 = __expf(-2.f*fabsf(tp));
        float tv = (1.f - e2) * rcp_nr(1.f + e2);
        tv = (tp < 0.f) ? -tv : tv;
        hb[q] = zv*hreg[nt][q] + (1.f - zv)*tv;
        hb4[q] = (short)f2bf(hb[q]);
      }
      *reinterpret_cast<bf4*>(smem + hb16w + nt*32) = hb4;
      *reinterpret_cast<unsigned*>(smem + hb8w + nt*16) = pack_fp8x4(hb);
    }
    asm volatile("s_waitcnt lgkmcnt(0)" ::: "memory");
    __builtin_amdgcn_s_barrier();
    asm volatile("" ::: "memory");

    // ---- phase 2: mean (bf16, wdm) + logvar (fp8, wdl8) — all resident
    f32x4 apm[2], apl[2];
    apm[0] = unpack4(*reinterpret_cast<const bf4*>(bias_lds + 256 + cl));
    apm[1] = unpack4(*reinterpret_cast<const bf4*>(bias_lds + 256 + cl + 16));
    apl[0] = unpack4(*reinterpret_cast<const bf4*>(bias_lds + 512 + cl));
    apl[1] = unpack4(*reinterpret_cast<const bf4*>(bias_lds + 512 + cl + 16));
    #pragma unroll
    for (int ks = 0; ks < 8; ++ks){
      short8 hbB = *reinterpret_cast<const short8*>(smem + hb16r + ks*64);
      u64_t  hb8 = *reinterpret_cast<const u64_t*>(smem + hb8r + ks*32);
      apm[0] = MFMA_B16(wdm[0][ks], hbB, apm[0]); apm[1] = MFMA_B16(wdm[1][ks], hbB, apm[1]);
      apl[0] = MFMA_F8(wdl8[0][ks], hb8, apl[0]); apl[1] = MFMA_F8(wdl8[1][ks], hb8, apl[1]);
    }

    // ---- sample + write h
    #pragma unroll
    for (int nt = 0; nt < 2; ++nt){
      f32x4 epsv = unpack4(epsp[nt]);
      bf4 s4;
      f32x4 sf;
      #pragma unroll
      for (int q = 0; q < 4; ++q){
        float mean = fminf(fmaxf(apm[nt][q], -1000.f), 1000.f);
        float lvv  = fminf(fmaxf(apl[nt][q], -30.f),   30.f);
        float s = mean + __expf(0.5f*lvv)*epsv[q];
        hreg[nt][q] = s;
        sf[q] = s;
        s4[q] = (short)f2bf(s);
      }
      int c = cl + 16*nt;
      *reinterpret_cast<bf4*>(smem + h16w + nt*32) = s4;
      *reinterpret_cast<unsigned*>(smem + h8w + nt*16) = pack_fp8x4(sf);
      size_t oi = obase + 16*nt;
      if (b16){
        *reinterpret_cast<bf4*>(o16 + oi) = s4;
        if (t == 1023) *reinterpret_cast<bf4*>(o16 + 16777216u + (size_t)(b0+lr)*256 + c) = s4;
      } else {
        *reinterpret_cast<f32x4*>(o32 + oi) = sf;
        if (t == 1023) *reinterpret_cast<f32x4*>(o32 + 16777216u + (size_t)(b0+lr)*256 + c) = sf;
      }
    }
    asm volatile("s_waitcnt lgkmcnt(0)" ::: "memory");
    __builtin_amdgcn_s_barrier();
    asm volatile("" ::: "memory");

    apt += 768; ept += 256; obase += 256;
  }
}

// ---------------------------------------------------------------- host
extern "C" void kernel_launch(void* const* d_in, const int* in_sizes, int n_in,
                              void* d_out, int out_size, void* d_ws, size_t ws_size,
                              hipStream_t stream)
{
  const void* x   = d_in[0];
  const void* h0  = d_in[1];
  const void* eps = d_in[2];
  const void* Wz  = d_in[3];
  const void* bz  = d_in[4];
  const void* Wr  = d_in[5];
  const void* br  = d_in[6];
  const void* Wtx = d_in[7];
  const void* btx = d_in[8];
  const void* Wth = d_in[9];
  const void* bth = d_in[10];
  const void* Wd  = d_in[11];
  const void* bd  = d_in[12];
  ushort_t* ws16 = (ushort_t*)d_ws;
  uint_t* flag = (uint_t*)((char*)d_ws + FLAG_BYTE);
  const ushort_t* aux = ws16 + AUX_OFF;
  unsigned char* f8w = (unsigned char*)d_ws + F8_OFF_BYTES;
  ushort_t* Ax = (ushort_t*)((char*)d_ws + AX_OFF_BYTES);
  ushort_t* eps16 = (ushort_t*)((char*)d_ws + EPS_OFF_BYTES);

  detect_kernel<<<dim3(1), dim3(64), 0, stream>>>((const uint_t*)x, flag);
  prep_kernel<<<dim3(2118), dim3(256), 0, stream>>>(Wz, Wr, Wtx, Wth, Wd,
                                                    bz, br, btx, bth, bd, h0,
                                                    flag, ws16);
  prep_f8_kernel<<<dim3(192), dim3(256), 0, stream>>>(ws16, f8w);
  epscvt_kernel<<<dim3(8192), dim3(256), 0, stream>>>(eps, flag, eps16);
  xproj_kernel<<<dim3(3072), dim3(256), 0, stream>>>(x, ws16, aux, flag, Ax);

  (void)hipFuncSetAttribute(reinterpret_cast<const void*>(&gru_kernel),
                            hipFuncAttributeMaxDynamicSharedMemorySize, SMEM_REC);
  gru_kernel<<<dim3(4), dim3(512), SMEM_REC, stream>>>(ws16, f8w, Ax, eps16, flag, d_out);
}

// Round 13
// 3683.003 us; speedup vs baseline: 2.3131x; 1.0850x over previous
//
#include <hip/hip_runtime.h>
#include <hip/hip_bf16.h>

typedef unsigned short ushort_t;
typedef unsigned int uint_t;
typedef unsigned long long u64_t;
using f32x4 = __attribute__((ext_vector_type(4))) float;
using bf4 = __attribute__((ext_vector_type(4))) short;
using short8 = __attribute__((ext_vector_type(8))) short;

#define MFMA_B16(a,b,c) __builtin_amdgcn_mfma_f32_16x16x32_bf16((a),(b),(c),0,0,0)
#define MFMA_F8(a,b,c)  __builtin_amdgcn_mfma_f32_16x16x32_fp8_fp8((long)(a),(long)(b),(c),0,0,0)

static __device__ __forceinline__ float bf2f(ushort_t u){
  unsigned v = ((unsigned)u) << 16;
  return __builtin_bit_cast(float, v);
}
static __device__ __forceinline__ ushort_t f2bf(float f){
  __hip_bfloat16 h = __float2bfloat16(f);
  return __builtin_bit_cast(unsigned short, h);
}
static __device__ __forceinline__ f32x4 unpack4(bf4 v){
  f32x4 r;
  r[0]=bf2f((ushort_t)v[0]); r[1]=bf2f((ushort_t)v[1]);
  r[2]=bf2f((ushort_t)v[2]); r[3]=bf2f((ushort_t)v[3]);
  return r;
}
static __device__ __forceinline__ unsigned pack_fp8x4(f32x4 f){
  unsigned u = __builtin_amdgcn_cvt_pk_fp8_f32(f[0], f[1], 0, false);
  u = __builtin_amdgcn_cvt_pk_fp8_f32(f[2], f[3], u, true);
  return u;
}
// reciprocal with one Newton step: rel err ~2^-28 (numerically = exact div here)
static __device__ __forceinline__ float rcp_nr(float x){
  float r = __builtin_amdgcn_rcpf(x);
  return r * (2.f - x*r);
}

// ws layout:
//   [0, 524288) elems  : bf16 weights, 2048 rows x 256 k (row-major)
//       rows 0-767: xproj B (Wzx^T|Wrx^T|Wtx^T); 768: Wzh^T; 1024: Wrh^T;
//       1280: Wth^T; 1536-2047: Wd^T (1536-1791 mean, 1792-2047 logvar)
//   [524288, 542208)   : bf16 aux (bz|br|btx|bth|bd|h0)
//   byte 1084416       : uint flag (1 = inputs bf16, 0 = f32)
//   byte 1088512       : fp8 weights: Wrh 64K | Wth 64K | Wd_lv 64K
//   byte 2 MB          : Ax bf16 (65536 x 768)
//   byte 112 MB        : eps bf16 (16777216)
#define W_ELEMS  524288
#define AUX_OFF  524288
#define AUX_BTH  768
#define AUX_BD   1024
#define AUX_H0   1536
#define FLAG_BYTE 1084416u
#define F8_OFF_BYTES  1088512u
#define AX_OFF_BYTES  (2u<<20)
#define EPS_OFF_BYTES (112u<<20)
#define ROW_ZH 768
#define ROW_RH 1024
#define ROW_TH 1280
#define ROW_D  1536

// gru LDS map (bytes). Linear-padded rows: bf16 stride 528 (132 dwords = 4 mod
// 32), fp8 stride 264 (66 dwords = 2 mod 32). k-loop reads are base + ks*imm.
// Biases stored as f32 (direct b128 accumulator init, no unpack).
#define L_WZ    0         // 256 x 528 (Wzh^T bf16)
#define L_H16   135168    // 16 x 528 (h bf16)
#define L_HB16  143616    // 16 x 528 (h_base bf16)
#define L_H8    152064    // 16 x 264 (h fp8)
#define L_HB8   156288    // 16 x 264 (h_base fp8)
#define L_BIAS  160512    // f32: bth[256] | bd[512]  (3072 B)
#define SMEM_REC 163584

// ---------------------------------------------------------------- dtype detect
__global__ __launch_bounds__(64) void detect_kernel(const uint_t* __restrict__ x,
                                                    uint_t* __restrict__ flag)
{
  int l = threadIdx.x;
  int cnt = 0;
  for (int i = 0; i < 8; ++i){
    uint_t w = x[i*64 + l];
    uint_t e = (w >> 7) & 0xFF;
    unsigned long long m = __ballot(e >= 100 && e <= 136);
    if (l == 0) cnt += __popcll(m);
  }
  if (l == 0) *flag = (cnt >= 256) ? 1u : 0u;
}

// ---------------------------------------------------------------- prep (canonicalize to bf16)
__global__ __launch_bounds__(256) void prep_kernel(
    const void* __restrict__ Wz, const void* __restrict__ Wr,
    const void* __restrict__ Wtx, const void* __restrict__ Wth,
    const void* __restrict__ Wd,
    const void* __restrict__ bz, const void* __restrict__ br,
    const void* __restrict__ btx, const void* __restrict__ bth,
    const void* __restrict__ bd, const void* __restrict__ h0,
    const uint_t* __restrict__ flag, ushort_t* __restrict__ o)
{
  const bool b16 = (*flag != 0);
  int i = blockIdx.x * 256 + threadIdx.x;          // < 542208
  const void* src; int idx;
  if (i < W_ELEMS){
    int row = i >> 8, k = i & 255;
    if      (row <  256){ src = Wz;  idx = k*256 + row;         }
    else if (row <  512){ src = Wr;  idx = k*256 + (row-256);   }
    else if (row <  768){ src = Wtx; idx = k*256 + (row-512);   }
    else if (row < 1024){ src = Wz;  idx = (256+k)*256 + (row-768);  }
    else if (row < 1280){ src = Wr;  idx = (256+k)*256 + (row-1024); }
    else if (row < 1536){ src = Wth; idx = k*256 + (row-1280);  }
    else                { src = Wd;  idx = k*512 + (row-1536);  }
  } else {
    int j = i - W_ELEMS;
    if      (j <  256){ src = bz;  idx = j;       }
    else if (j <  512){ src = br;  idx = j-256;   }
    else if (j <  768){ src = btx; idx = j-512;   }
    else if (j < 1024){ src = bth; idx = j-768;   }
    else if (j < 1536){ src = bd;  idx = j-1024;  }
    else              { src = h0;  idx = j-1536;  }
  }
  o[i] = b16 ? ((const ushort_t*)src)[idx] : f2bf(((const float*)src)[idx]);
}

// ---------------------------------------------------------------- prep fp8 (Wrh|Wth|Wd_lv)
__global__ __launch_bounds__(256) void prep_f8_kernel(
    const ushort_t* __restrict__ ws, unsigned char* __restrict__ o)
{
  int i = blockIdx.x * 256 + threadIdx.x;          // < 49152, 4 elems each
  int m = i >> 14;                                 // region 0,1,2
  int b = (i & 16383) * 4;                         // byte offset in 64K region
  int row = b >> 8, k = b & 255;
  int srow = (m == 0) ? (ROW_RH + row) : (m == 1) ? (ROW_TH + row) : (ROW_D + 256 + row);
  f32x4 f = unpack4(*reinterpret_cast<const bf4*>(ws + srow*256 + k));
  *reinterpret_cast<unsigned*>(o + (size_t)i*4) = pack_fp8x4(f);
}

// ---------------------------------------------------------------- eps -> bf16
__global__ __launch_bounds__(256) void epscvt_kernel(
    const void* __restrict__ eps, const uint_t* __restrict__ flag,
    ushort_t* __restrict__ o)
{
  const bool b16 = (*flag != 0);
  int i = blockIdx.x * 256 + threadIdx.x;          // 8 elems each, 16777216 total
  if (b16){
    short8 v = reinterpret_cast<const short8*>(eps)[i];
    reinterpret_cast<short8*>(o)[i] = v;
  } else {
    const f32x4* e = reinterpret_cast<const f32x4*>(eps) + i*2;
    f32x4 a = e[0], b = e[1];
    short8 v;
    v[0]=(short)f2bf(a[0]); v[1]=(short)f2bf(a[1]); v[2]=(short)f2bf(a[2]); v[3]=(short)f2bf(a[3]);
    v[4]=(short)f2bf(b[0]); v[5]=(short)f2bf(b[1]); v[6]=(short)f2bf(b[2]); v[7]=(short)f2bf(b[3]);
    reinterpret_cast<short8*>(o)[i] = v;
  }
}

// ---------------------------------------------------------------- x projection GEMM
__global__ __launch_bounds__(256) void xproj_kernel(
    const void* __restrict__ x, const ushort_t* __restrict__ wsB,
    const ushort_t* __restrict__ aux, const uint_t* __restrict__ flag,
    ushort_t* __restrict__ Ax)
{
  __shared__ ushort_t As[32768];
  const bool b16 = (*flag != 0);
  const int tid = threadIdx.x, w = tid >> 6, l = tid & 63, lr = l & 15, lg = l >> 4;
  const int mt = blockIdx.x % 512, nb = blockIdx.x / 512;
  const int m0 = mt * 128, n0 = nb * 128;

  #pragma unroll
  for (int i = 0; i < 16; ++i){
    int gidx = i*256 + tid, row = gidx >> 5, g = gidx & 31;
    short8 v;
    if (b16){
      v = *reinterpret_cast<const short8*>((const ushort_t*)x + (m0+row)*256 + g*8);
    } else {
      const f32x4* xf = reinterpret_cast<const f32x4*>((const float*)x + (m0+row)*256 + g*8);
      f32x4 a0 = xf[0], a1 = xf[1];
      v[0]=(short)f2bf(a0[0]); v[1]=(short)f2bf(a0[1]); v[2]=(short)f2bf(a0[2]); v[3]=(short)f2bf(a0[3]);
      v[4]=(short)f2bf(a1[0]); v[5]=(short)f2bf(a1[1]); v[6]=(short)f2bf(a1[2]); v[7]=(short)f2bf(a1[3]);
    }
    *reinterpret_cast<short8*>(reinterpret_cast<char*>(As) + row*512 + ((g ^ (row&7)) << 4)) = v;
  }
  __syncthreads();

  const int wr = w >> 1, wc = w & 1;
  f32x4 acc[4][4];
  #pragma unroll
  for (int a = 0; a < 4; ++a)
    #pragma unroll
    for (int b = 0; b < 4; ++b) acc[a][b] = (f32x4){0.f,0.f,0.f,0.f};

  #pragma unroll
  for (int ks = 0; ks < 8; ++ks){
    short8 av[4], bv[4];
    #pragma unroll
    for (int mi = 0; mi < 4; ++mi){
      int rT = 64*wr + 16*mi + lr, g = ks*4 + lg;
      av[mi] = *reinterpret_cast<const short8*>(reinterpret_cast<const char*>(As) + rT*512 + ((g ^ (rT&7)) << 4));
    }
    #pragma unroll
    for (int ni = 0; ni < 4; ++ni){
      int nr = n0 + 64*wc + 16*ni + lr;
      bv[ni] = *reinterpret_cast<const short8*>(wsB + nr*256 + ks*32 + lg*8);
    }
    #pragma unroll
    for (int mi = 0; mi < 4; ++mi)
      #pragma unroll
      for (int ni = 0; ni < 4; ++ni)
        acc[mi][ni] = MFMA_B16(av[mi], bv[ni], acc[mi][ni]);
  }

  #pragma unroll
  for (int ni = 0; ni < 4; ++ni){
    int c = n0 + 64*wc + 16*ni + lr;
    float bias = bf2f(aux[c]);
    #pragma unroll
    for (int mi = 0; mi < 4; ++mi)
      #pragma unroll
      for (int j = 0; j < 4; ++j){
        int m = m0 + 64*wr + 16*mi + lg*4 + j;
        Ax[m*768 + c] = f2bf(acc[mi][ni][j] + bias);
      }
  }
}

// ---------------------------------------------------------------- recurrent kernel
// 4 WGs x 512 threads (8 waves, 2/SIMD, 128-VGPR budget). WG owns batch rows
// [16*bid,+16); wave w owns cols [32w,32w+32). Operand-swapped MFMA:
// D = W(A) x h(B); lane holds (batch=lane&15, cols = 32w+16nt+(lane>>4)*4+q).
// ALL weights resident: Wzh bf16 in LDS; Wrh/Wth/Wd_lv fp8 + Wd_mean bf16 in
// regs. Per-step VMEM = Ax (6xb64) + eps (2xb64). Biases f32 in LDS (direct
// b128 accumulator init). Tail state write hoisted out of the t-loop.
__global__ void __launch_bounds__(512, 1) gru_kernel(
    const ushort_t* __restrict__ ws16, const unsigned char* __restrict__ f8w,
    const ushort_t* __restrict__ Ax, const ushort_t* __restrict__ eps16,
    const uint_t* __restrict__ flag, void* __restrict__ outp)
{
  extern __shared__ char smem[];
  const bool b16 = (*flag != 0);
  ushort_t* o16 = (ushort_t*)outp;
  float*    o32 = (float*)outp;
  const ushort_t* aux = ws16 + AUX_OFF;
  float* bias_f = (float*)(smem + L_BIAS);
  const int tid = threadIdx.x, w = tid >> 6, l = tid & 63, lr = l & 15, lg = l >> 4;
  const int b0 = blockIdx.x * 16;
  const int c0 = 32 * w;
  const int cl = c0 + lg*4;                 // lane's col base (nt=0)

  // stage Wzh^T into LDS (linear, 528 B row stride)
  for (int gi = tid; gi < 8192; gi += 512){
    int row = gi >> 5, g = gi & 31;
    short8 v = *reinterpret_cast<const short8*>(ws16 + (ROW_ZH + row)*256 + g*8);
    *reinterpret_cast<short8*>(smem + row*528 + g*16) = v;
  }
  if (tid < 256) bias_f[tid] = bf2f(aux[AUX_BTH + tid]);
  if (tid < 512) bias_f[256 + tid] = bf2f(aux[AUX_BD + tid]);

  // resident weight fragments
  const unsigned char* f_rh = f8w;
  const unsigned char* f_th = f8w + 65536;
  const unsigned char* f_dl = f8w + 131072;
  u64_t wrh8[2][8], wth8[2][8], wdl8[2][8];
  short8 wdm[2][8];
  #pragma unroll
  for (int nt = 0; nt < 2; ++nt){
    int r = c0 + 16*nt + lr;
    #pragma unroll
    for (int ks = 0; ks < 8; ++ks){
      wrh8[nt][ks] = *reinterpret_cast<const u64_t*>(f_rh + r*256 + ks*32 + lg*8);
      wth8[nt][ks] = *reinterpret_cast<const u64_t*>(f_th + r*256 + ks*32 + lg*8);
      wdl8[nt][ks] = *reinterpret_cast<const u64_t*>(f_dl + r*256 + ks*32 + lg*8);
      wdm[nt][ks]  = *reinterpret_cast<const short8*>(ws16 + (ROW_D + r)*256 + ks*32 + lg*8);
    }
  }

  // per-lane LDS stream bases (t-invariant)
  const int wzr0 = L_WZ + (c0 + lr)*528 + lg*16;
  const int wzr1 = L_WZ + (c0 + 16 + lr)*528 + lg*16;
  const int h16r = L_H16 + lr*528 + lg*16;
  const int hb16r= L_HB16+ lr*528 + lg*16;
  const int h8r  = L_H8  + lr*264 + lg*8;
  const int hb8r = L_HB8 + lr*264 + lg*8;
  const int h16w = L_H16 + lr*528 + cl*2;
  const int hb16w= L_HB16+ lr*528 + cl*2;
  const int h8w  = L_H8  + lr*264 + cl;
  const int hb8w = L_HB8 + lr*264 + cl;

  // h in fp32 regs; lane holds (batch=lr, cols cl+16nt+q)
  f32x4 hreg[2];
  #pragma unroll
  for (int nt = 0; nt < 2; ++nt){
    int c = cl + 16*nt;
    hreg[nt] = unpack4(*reinterpret_cast<const bf4*>(aux + AUX_H0 + (b0+lr)*256 + c));
    bf4 hv;
    hv[0]=(short)f2bf(hreg[nt][0]); hv[1]=(short)f2bf(hreg[nt][1]);
    hv[2]=(short)f2bf(hreg[nt][2]); hv[3]=(short)f2bf(hreg[nt][3]);
    *reinterpret_cast<bf4*>(smem + h16w + nt*32) = hv;
    *reinterpret_cast<unsigned*>(smem + h8w + nt*16) = pack_fp8x4(hreg[nt]);
  }
  __syncthreads();

  const ushort_t* apt = Ax    + (size_t)(b0+lr)*1024*768 + cl;
  const ushort_t* ept = eps16 + (size_t)(b0+lr)*1024*256 + cl;
  size_t obase = (size_t)(b0+lr)*262144 + cl;

  for (int t = 0; t < 1024; ++t){
    // this step's global loads (8 x b64), issued up front, consumed late
    bf4 axzp[2], axrp[2], axtp[2], epsp[2];
    #pragma unroll
    for (int nt = 0; nt < 2; ++nt){
      axzp[nt] = *reinterpret_cast<const bf4*>(apt + 16*nt);
      axrp[nt] = *reinterpret_cast<const bf4*>(apt + 256 + 16*nt);
      axtp[nt] = *reinterpret_cast<const bf4*>(apt + 512 + 16*nt);
      epsp[nt] = *reinterpret_cast<const bf4*>(ept + 16*nt);
    }

    // ---- phase 1: z (bf16), r (fp8), h@Wth (fp8)
    f32x4 az[2], ar[2], at[2];
    az[0] = (f32x4){0.f,0.f,0.f,0.f}; az[1] = az[0];
    ar[0] = az[0]; ar[1] = az[0];
    at[0] = *reinterpret_cast<const f32x4*>(bias_f + cl);
    at[1] = *reinterpret_cast<const f32x4*>(bias_f + cl + 16);
    #pragma unroll
    for (int ks = 0; ks < 8; ++ks){
      short8 hB = *reinterpret_cast<const short8*>(smem + h16r + ks*64);
      u64_t  h8 = *reinterpret_cast<const u64_t*>(smem + h8r + ks*32);
      short8 wz0 = *reinterpret_cast<const short8*>(smem + wzr0 + ks*64);
      short8 wz1 = *reinterpret_cast<const short8*>(smem + wzr1 + ks*64);
      az[0] = MFMA_B16(wz0, hB, az[0]);        az[1] = MFMA_B16(wz1, hB, az[1]);
      ar[0] = MFMA_F8(wrh8[0][ks], h8, ar[0]); ar[1] = MFMA_F8(wrh8[1][ks], h8, ar[1]);
      at[0] = MFMA_F8(wth8[0][ks], h8, at[0]); at[1] = MFMA_F8(wth8[1][ks], h8, at[1]);
    }

    // activations -> h_base (bf16 + fp8 copies into LDS)
    // h_base = zv*(h + ez*tv) with zv = 1/(1+ez), since 1-zv = ez*zv.
    #pragma unroll
    for (int nt = 0; nt < 2; ++nt){
      f32x4 axz = unpack4(axzp[nt]), axr = unpack4(axrp[nt]), axt = unpack4(axtp[nt]);
      f32x4 hb;
      bf4 hb4;
      #pragma unroll
      for (int q = 0; q < 4; ++q){
        float zp = az[nt][q] + axz[q];
        float rp = ar[nt][q] + axr[q];
        float ez = __expf(-zp);
        float zv = rcp_nr(1.f + ez);
        float rv = rcp_nr(1.f + __expf(-rp));
        float tp = axt[q] + rv*at[nt][q];
        float e2 = __expf(-2.f*fabsf(tp));
        float tv = (1.f - e2) * rcp_nr(1.f + e2);
        tv = (tp < 0.f) ? -tv : tv;
        hb[q] = zv * __builtin_fmaf(ez, tv, hreg[nt][q]);
        hb4[q] = (short)f2bf(hb[q]);
      }
      *reinterpret_cast<bf4*>(smem + hb16w + nt*32) = hb4;
      *reinterpret_cast<unsigned*>(smem + hb8w + nt*16) = pack_fp8x4(hb);
    }
    asm volatile("s_waitcnt lgkmcnt(0)" ::: "memory");
    __builtin_amdgcn_s_barrier();
    asm volatile("" ::: "memory");

    // ---- phase 2: mean (bf16, wdm) + logvar (fp8, wdl8) — all resident
    f32x4 apm[2], apl[2];
    apm[0] = *reinterpret_cast<const f32x4*>(bias_f + 256 + cl);
    apm[1] = *reinterpret_cast<const f32x4*>(bias_f + 256 + cl + 16);
    apl[0] = *reinterpret_cast<const f32x4*>(bias_f + 512 + cl);
    apl[1] = *reinterpret_cast<const f32x4*>(bias_f + 512 + cl + 16);
    #pragma unroll
    for (int ks = 0; ks < 8; ++ks){
      short8 hbB = *reinterpret_cast<const short8*>(smem + hb16r + ks*64);
      u64_t  hb8 = *reinterpret_cast<const u64_t*>(smem + hb8r + ks*32);
      apm[0] = MFMA_B16(wdm[0][ks], hbB, apm[0]); apm[1] = MFMA_B16(wdm[1][ks], hbB, apm[1]);
      apl[0] = MFMA_F8(wdl8[0][ks], hb8, apl[0]); apl[1] = MFMA_F8(wdl8[1][ks], hb8, apl[1]);
    }

    // ---- sample + write h
    #pragma unroll
    for (int nt = 0; nt < 2; ++nt){
      f32x4 epsv = unpack4(epsp[nt]);
      bf4 s4;
      f32x4 sf;
      #pragma unroll
      for (int q = 0; q < 4; ++q){
        float mean = fminf(fmaxf(apm[nt][q], -1000.f), 1000.f);
        float lvv  = fminf(fmaxf(apl[nt][q], -30.f),   30.f);
        float s = mean + __expf(0.5f*lvv)*epsv[q];
        hreg[nt][q] = s;
        sf[q] = s;
        s4[q] = (short)f2bf(s);
      }
      *reinterpret_cast<bf4*>(smem + h16w + nt*32) = s4;
      *reinterpret_cast<unsigned*>(smem + h8w + nt*16) = pack_fp8x4(sf);
      size_t oi = obase + 16*nt;
      if (b16){
        *reinterpret_cast<bf4*>(o16 + oi) = s4;
      } else {
        *reinterpret_cast<f32x4*>(o32 + oi) = sf;
      }
    }
    asm volatile("s_waitcnt lgkmcnt(0)" ::: "memory");
    __builtin_amdgcn_s_barrier();
    asm volatile("" ::: "memory");

    apt += 768; ept += 256; obase += 256;
  }

  // ---- tail: final hidden state (t = 1023) from hreg
  #pragma unroll
  for (int nt = 0; nt < 2; ++nt){
    int c = cl + 16*nt;
    size_t o2 = 16777216u + (size_t)(b0+lr)*256 + c;
    if (b16){
      bf4 s4;
      s4[0]=(short)f2bf(hreg[nt][0]); s4[1]=(short)f2bf(hreg[nt][1]);
      s4[2]=(short)f2bf(hreg[nt][2]); s4[3]=(short)f2bf(hreg[nt][3]);
      *reinterpret_cast<bf4*>(o16 + o2) = s4;
    } else {
      *reinterpret_cast<f32x4*>(o32 + o2) = hreg[nt];
    }
  }
}

// ---------------------------------------------------------------- host
extern "C" void kernel_launch(void* const* d_in, const int* in_sizes, int n_in,
                              void* d_out, int out_size, void* d_ws, size_t ws_size,
                              hipStream_t stream)
{
  const void* x   = d_in[0];
  const void* h0  = d_in[1];
  const void* eps = d_in[2];
  const void* Wz  = d_in[3];
  const void* bz  = d_in[4];
  const void* Wr  = d_in[5];
  const void* br  = d_in[6];
  const void* Wtx = d_in[7];
  const void* btx = d_in[8];
  const void* Wth = d_in[9];
  const void* bth = d_in[10];
  const void* Wd  = d_in[11];
  const void* bd  = d_in[12];
  ushort_t* ws16 = (ushort_t*)d_ws;
  uint_t* flag = (uint_t*)((char*)d_ws + FLAG_BYTE);
  const ushort_t* aux = ws16 + AUX_OFF;
  unsigned char* f8w = (unsigned char*)d_ws + F8_OFF_BYTES;
  ushort_t* Ax = (ushort_t*)((char*)d_ws + AX_OFF_BYTES);
  ushort_t* eps16 = (ushort_t*)((char*)d_ws + EPS_OFF_BYTES);

  detect_kernel<<<dim3(1), dim3(64), 0, stream>>>((const uint_t*)x, flag);
  prep_kernel<<<dim3(2118), dim3(256), 0, stream>>>(Wz, Wr, Wtx, Wth, Wd,
                                                    bz, br, btx, bth, bd, h0,
                                                    flag, ws16);
  prep_f8_kernel<<<dim3(192), dim3(256), 0, stream>>>(ws16, f8w);
  epscvt_kernel<<<dim3(8192), dim3(256), 0, stream>>>(eps, flag, eps16);
  xproj_kernel<<<dim3(3072), dim3(256), 0, stream>>>(x, ws16, aux, flag, Ax);

  (void)hipFuncSetAttribute(reinterpret_cast<const void*>(&gru_kernel),
                            hipFuncAttributeMaxDynamicSharedMemorySize, SMEM_REC);
  gru_kernel<<<dim3(4), dim3(512), SMEM_REC, stream>>>(ws16, f8w, Ax, eps16, flag, d_out);
}